// Round 6
// baseline (3294.545 us; speedup 1.0000x reference)
//
#include <hip/hip_runtime.h>
#include <math.h>

#define BB 8
#define NN 2048
#define KNB 20

// ---------------------------------------------------------------- sq
__global__ __launch_bounds__(256) void sq_kernel(const float* __restrict__ x, int bs, int C,
                                                 float* __restrict__ sq) {
  int t = blockIdx.x * blockDim.x + threadIdx.x;
  int b = t / NN, n = t % NN;
  const float* xp = x + (size_t)b * bs + n;
  float s = 0.f;
  for (int c = 0; c < C; ++c) { float v = xp[c * NN]; s += v * v; }
  sq[t] = s;
}

// ---------------------------------------------------------------- M = wk^T wq
__global__ __launch_bounds__(256) void mprep_kernel(const float* __restrict__ wq,
                                                    const float* __restrict__ wk, int C,
                                                    float* __restrict__ M) {
  int T = blockIdx.x * 256 + threadIdx.x;
  if (T >= C * C) return;
  int c = T / C, cp = T % C;
  float a = 0.f;
  for (int e = 0; e < C; ++e) a += wk[e * C + c] * wq[e * C + cp];
  M[c * C + cp] = a;
}

// ---------------------------------------------------------------- transpose
__global__ __launch_bounds__(256) void transpose_kernel(const float* __restrict__ in, int inBS,
                                                        int R, int Cl, float* __restrict__ out) {
  __shared__ float tile[32][33];
  int b = blockIdx.z;
  const float* ip = in + (size_t)b * inBS;
  float* op = out + (size_t)b * R * Cl;
  int c0 = blockIdx.x * 32, r0 = blockIdx.y * 32;
  int tx = threadIdx.x & 31, ty = threadIdx.x >> 5;
  for (int yy = ty; yy < 32; yy += 8) {
    int r = r0 + yy, c = c0 + tx;
    tile[yy][tx] = (r < R && c < Cl) ? ip[(size_t)r * Cl + c] : 0.f;
  }
  __syncthreads();
  for (int yy = ty; yy < 32; yy += 8) {
    int c = c0 + yy, r = r0 + tx;
    if (c < Cl && r < R) op[(size_t)c * R + r] = tile[tx][yy];
  }
}

// ---------------------------------------------------------------- pd GEMM 128-tile, double-buffered
// P[bl][n][m] = 2*sum_c x[c][n]*x[c][m] - sq[m]
__global__ __launch_bounds__(256, 3) void pd_gemm128_db_kernel(
    const float* __restrict__ x, int bs, int C, const float* __restrict__ sq,
    float* __restrict__ P, int b_base) {
  const int b = b_base + blockIdx.z;
  const int n0 = blockIdx.x * 128, m0 = blockIdx.y * 128;
  const int tid = threadIdx.x;
  const int tm = tid & 15, tn = tid >> 4;
  __shared__ float As[2][16][128], Bs[2][16][128];
  const float* xb = x + (size_t)b * bs;
  float acc[8][8];
#pragma unroll
  for (int i = 0; i < 8; ++i)
#pragma unroll
    for (int j = 0; j < 8; ++j) acc[i][j] = 0.f;

  float4 ara[2], arb[2];
  auto load_tile = [&](int k0) {
#pragma unroll
    for (int it = 0; it < 2; ++it) {
      int i = it * 256 + tid;
      int kc = i >> 5, c4 = i & 31;
      bool ok = (k0 + kc) < C;
      ara[it] = ok ? *(const float4*)&xb[(size_t)(k0 + kc) * NN + n0 + c4 * 4]
                   : make_float4(0.f, 0.f, 0.f, 0.f);
      arb[it] = ok ? *(const float4*)&xb[(size_t)(k0 + kc) * NN + m0 + c4 * 4]
                   : make_float4(0.f, 0.f, 0.f, 0.f);
    }
  };
  auto store_tile = [&](int buf) {
#pragma unroll
    for (int it = 0; it < 2; ++it) {
      int i = it * 256 + tid;
      int kc = i >> 5, c4 = i & 31;
      *(float4*)&As[buf][kc][c4 * 4] = ara[it];
      *(float4*)&Bs[buf][kc][c4 * 4] = arb[it];
    }
  };

  load_tile(0);
  store_tile(0);
  int cur = 0;
  for (int k0 = 0; k0 < C; k0 += 16) {
    bool more = (k0 + 16) < C;
    if (more) load_tile(k0 + 16);
    __syncthreads();
#pragma unroll
    for (int kc = 0; kc < 16; ++kc) {
      float4 a0 = *(const float4*)&As[cur][kc][tn * 4];
      float4 a1 = *(const float4*)&As[cur][kc][64 + tn * 4];
      float4 b0 = *(const float4*)&Bs[cur][kc][tm * 4];
      float4 b1 = *(const float4*)&Bs[cur][kc][64 + tm * 4];
      float ar[8] = {a0.x, a0.y, a0.z, a0.w, a1.x, a1.y, a1.z, a1.w};
      float br[8] = {b0.x, b0.y, b0.z, b0.w, b1.x, b1.y, b1.z, b1.w};
#pragma unroll
      for (int i = 0; i < 8; ++i)
#pragma unroll
        for (int j = 0; j < 8; ++j) acc[i][j] += ar[i] * br[j];
    }
    if (more) store_tile(cur ^ 1);
    cur ^= 1;
  }
  float4 sqa = *(const float4*)&sq[b * NN + m0 + tm * 4];
  float4 sqb = *(const float4*)&sq[b * NN + m0 + 64 + tm * 4];
#pragma unroll
  for (int h = 0; h < 2; ++h)
#pragma unroll
    for (int i = 0; i < 4; ++i) {
      int r = h * 4 + i;
      int nn = n0 + h * 64 + tn * 4 + i;
      float* prow = &P[((size_t)blockIdx.z * NN + nn) * NN + m0];
      float4 o0, o1;
      o0.x = 2.f * acc[r][0] - sqa.x; o0.y = 2.f * acc[r][1] - sqa.y;
      o0.z = 2.f * acc[r][2] - sqa.z; o0.w = 2.f * acc[r][3] - sqa.w;
      o1.x = 2.f * acc[r][4] - sqb.x; o1.y = 2.f * acc[r][5] - sqb.y;
      o1.z = 2.f * acc[r][6] - sqb.z; o1.w = 2.f * acc[r][7] - sqb.w;
      *(float4*)&prow[tm * 4] = o0;
      *(float4*)&prow[64 + tm * 4] = o1;
    }
}

// ---------------------------------------------------------------- one-wave top-20
__global__ __launch_bounds__(64) void topk_kernel(const float* __restrict__ P,
                                                  int* __restrict__ idx, int b_base) {
  const int n = blockIdx.x;
  const int bl = blockIdx.y;
  const int b = b_base + bl;
  const int lane = threadIdx.x;
  const float* row = P + ((size_t)bl * NN + n) * NN;
  const float4* rp = (const float4*)row;
  float v[32];
#pragma unroll
  for (int q = 0; q < 8; ++q) {
    float4 vv = rp[q * 64 + lane];
    int mb = q * 256 + lane * 4;
    v[q * 4 + 0] = (mb + 0 == n) ? -INFINITY : vv.x;
    v[q * 4 + 1] = (mb + 1 == n) ? -INFINITY : vv.y;
    v[q * 4 + 2] = (mb + 2 == n) ? -INFINITY : vv.z;
    v[q * 4 + 3] = (mb + 3 == n) ? -INFINITY : vv.w;
  }
  int* op = idx + (size_t)(b * NN + n) * KNB;
  for (int k = 0; k < KNB; ++k) {
    float bv = v[0]; int bj = 0;
#pragma unroll
    for (int j = 1; j < 32; ++j)
      if (v[j] > bv) { bv = v[j]; bj = j; }
    int bm = (bj >> 2) * 256 + lane * 4 + (bj & 3);
#pragma unroll
    for (int s = 32; s > 0; s >>= 1) {
      float ov = __shfl_down(bv, s);
      int om = __shfl_down(bm, s);
      if (ov > bv) { bv = ov; bm = om; }
    }
    bm = __shfl(bm, 0);
    if (lane == 0) op[k] = bm;
    if (((bm >> 2) & 63) == lane) {
      int jj = ((bm >> 8) << 2) | (bm & 3);
#pragma unroll
      for (int j = 0; j < 32; ++j)
        if (j == jj) v[j] = -INFINITY;
    }
  }
}

// ---------------------------------------------------------------- conv GEMM 64-tile (small O)
__global__ __launch_bounds__(256, 2) void conv_gemm_kernel(
    const float* __restrict__ in, int inBS, int C, int O,
    const float* __restrict__ w, float* __restrict__ z) {
  const int b = blockIdx.z;
  const int n0 = blockIdx.x * 64, o0 = blockIdx.y * 64;
  const int tid = threadIdx.x;
  const int tm = tid & 15, tn = tid >> 4;
  __shared__ float Ws[16][68];
  __shared__ float Xs[16][64];
  const float* ib = in + (size_t)b * inBS;
  float acc[4][4];
#pragma unroll
  for (int i = 0; i < 4; ++i)
#pragma unroll
    for (int j = 0; j < 4; ++j) acc[i][j] = 0.f;

  for (int k0 = 0; k0 < C; k0 += 16) {
    __syncthreads();
#pragma unroll
    for (int it = 0; it < 4; ++it) {
      int i = it * 256 + tid;
      int kc = i >> 6, nl = i & 63;
      Xs[kc][nl] = ((k0 + kc) < C) ? ib[(size_t)(k0 + kc) * NN + n0 + nl] : 0.f;
      int ol = i >> 4, kc2 = i & 15;
      Ws[kc2][ol] = ((o0 + ol) < O && (k0 + kc2) < C) ? w[(size_t)(o0 + ol) * C + k0 + kc2] : 0.f;
    }
    __syncthreads();
#pragma unroll
    for (int kc = 0; kc < 16; ++kc) {
      float4 a = *(const float4*)&Ws[kc][tn * 4];
      float4 bv = *(const float4*)&Xs[kc][tm * 4];
      acc[0][0] += a.x * bv.x; acc[0][1] += a.x * bv.y; acc[0][2] += a.x * bv.z; acc[0][3] += a.x * bv.w;
      acc[1][0] += a.y * bv.x; acc[1][1] += a.y * bv.y; acc[1][2] += a.y * bv.z; acc[1][3] += a.y * bv.w;
      acc[2][0] += a.z * bv.x; acc[2][1] += a.z * bv.y; acc[2][2] += a.z * bv.z; acc[2][3] += a.z * bv.w;
      acc[3][0] += a.w * bv.x; acc[3][1] += a.w * bv.y; acc[3][2] += a.w * bv.z; acc[3][3] += a.w * bv.w;
    }
  }
#pragma unroll
  for (int i = 0; i < 4; ++i) {
    int o = o0 + tn * 4 + i;
    if (o < O) {
      float4 ov;
      ov.x = acc[i][0]; ov.y = acc[i][1]; ov.z = acc[i][2]; ov.w = acc[i][3];
      *(float4*)&z[((size_t)b * O + o) * NN + n0 + tm * 4] = ov;
    }
  }
}

// ---------------------------------------------------------------- conv GEMM 128-tile, double-buffered
__global__ __launch_bounds__(256, 3) void conv_gemm128_db_kernel(
    const float* __restrict__ in, int inBS, int C, int O,
    const float* __restrict__ w, float* __restrict__ z) {
  const int b = blockIdx.z;
  const int n0 = blockIdx.x * 128, o0 = blockIdx.y * 128;
  const int tid = threadIdx.x;
  const int tm = tid & 15, tn = tid >> 4;
  __shared__ float Xs[2][16][128];
  __shared__ float Ws[2][16][132];
  const float* ib = in + (size_t)b * inBS;
  float acc[8][8];
#pragma unroll
  for (int i = 0; i < 8; ++i)
#pragma unroll
    for (int j = 0; j < 8; ++j) acc[i][j] = 0.f;

  float4 xr[2], wr[2];
  auto load_tile = [&](int k0) {
#pragma unroll
    for (int it = 0; it < 2; ++it) {
      int i = it * 256 + tid;
      int kc = i >> 5, c4 = i & 31;
      xr[it] = ((k0 + kc) < C) ? *(const float4*)&ib[(size_t)(k0 + kc) * NN + n0 + c4 * 4]
                               : make_float4(0.f, 0.f, 0.f, 0.f);
      int ol = i >> 2, kq = i & 3;
      wr[it] = ((k0 + kq * 4) < C) ? *(const float4*)&w[(size_t)(o0 + ol) * C + k0 + kq * 4]
                                   : make_float4(0.f, 0.f, 0.f, 0.f);
    }
  };
  auto store_tile = [&](int buf) {
#pragma unroll
    for (int it = 0; it < 2; ++it) {
      int i = it * 256 + tid;
      int kc = i >> 5, c4 = i & 31;
      *(float4*)&Xs[buf][kc][c4 * 4] = xr[it];
      int ol = i >> 2, kq = i & 3;
      Ws[buf][kq * 4 + 0][ol] = wr[it].x;
      Ws[buf][kq * 4 + 1][ol] = wr[it].y;
      Ws[buf][kq * 4 + 2][ol] = wr[it].z;
      Ws[buf][kq * 4 + 3][ol] = wr[it].w;
    }
  };

  load_tile(0);
  store_tile(0);
  int cur = 0;
  for (int k0 = 0; k0 < C; k0 += 16) {
    bool more = (k0 + 16) < C;
    if (more) load_tile(k0 + 16);
    __syncthreads();
#pragma unroll
    for (int kc = 0; kc < 16; ++kc) {
      float4 a0 = *(const float4*)&Ws[cur][kc][tn * 4];
      float4 a1 = *(const float4*)&Ws[cur][kc][64 + tn * 4];
      float4 b0 = *(const float4*)&Xs[cur][kc][tm * 4];
      float4 b1 = *(const float4*)&Xs[cur][kc][64 + tm * 4];
      float ar[8] = {a0.x, a0.y, a0.z, a0.w, a1.x, a1.y, a1.z, a1.w};
      float br[8] = {b0.x, b0.y, b0.z, b0.w, b1.x, b1.y, b1.z, b1.w};
#pragma unroll
      for (int i = 0; i < 8; ++i)
#pragma unroll
        for (int j = 0; j < 8; ++j) acc[i][j] += ar[i] * br[j];
    }
    if (more) store_tile(cur ^ 1);
    cur ^= 1;
  }
#pragma unroll
  for (int h = 0; h < 2; ++h)
#pragma unroll
    for (int i = 0; i < 4; ++i) {
      int r = h * 4 + i;
      int o = o0 + h * 64 + tn * 4 + i;
      float* zrow = &z[((size_t)b * O + o) * NN + n0];
      float4 o0v, o1v;
      o0v.x = acc[r][0]; o0v.y = acc[r][1]; o0v.z = acc[r][2]; o0v.w = acc[r][3];
      o1v.x = acc[r][4]; o1v.y = acc[r][5]; o1v.z = acc[r][6]; o1v.w = acc[r][7];
      *(float4*)&zrow[tm * 4] = o0v;
      *(float4*)&zrow[64 + tm * 4] = o1v;
    }
}

// ---------------------------------------------------------------- attention (wave/point)
template <int C>
__global__ __launch_bounds__(64) void att_wave_kernel(
    const float* __restrict__ xT, const float* __restrict__ UT,
    const int* __restrict__ idx, float* __restrict__ AGGt) {
  const int n = blockIdx.x & (NN - 1);
  const int b = blockIdx.x >> 11;
  const int lane = threadIdx.x;
  constexpr int CP = C + 1;
  __shared__ float nb[KNB][CP];
  __shared__ float sl[KNB];
  __shared__ int nidx[KNB];
  __shared__ float ul[C];
  const float* xTb = xT + (size_t)b * NN * C;
  if (lane < KNB) nidx[lane] = idx[(size_t)(b * NN + n) * KNB + lane];
  for (int c = lane; c < C; c += 64) ul[c] = UT[((size_t)b * NN + n) * C + c];
  __syncthreads();
  for (int i = lane; i < KNB * C; i += 64) {
    int k = i / C, c = i - k * C;
    nb[k][c] = xTb[(size_t)nidx[k] * C + c];
  }
  __syncthreads();
  float sv = -INFINITY;
  if (lane < KNB) {
    float a = 0.f;
#pragma unroll
    for (int c = 0; c < C; ++c) a += nb[lane][c] * ul[c];
    sv = a / sqrtf((float)C);
  }
  float mx = sv;
#pragma unroll
  for (int s = 32; s > 0; s >>= 1) mx = fmaxf(mx, __shfl_xor(mx, s));
  float e = (lane < KNB) ? expf(sv - mx) : 0.f;
  float sum = e;
#pragma unroll
  for (int s = 32; s > 0; s >>= 1) sum += __shfl_xor(sum, s);
  if (lane < KNB) sl[lane] = e / sum;
  __syncthreads();
  const float* xTn = xTb + (size_t)n * C;
  float* op = AGGt + ((size_t)b * NN + n) * C;
  for (int c = lane; c < C; c += 64) {
    float a = 0.f;
#pragma unroll
    for (int k = 0; k < KNB; ++k) a += sl[k] * nb[k][c];
    op[c] = a - xTn[c];
  }
}

// ---------------------------------------------------------------- fused BN (+LReLU)
__global__ __launch_bounds__(256) void bn_fused_kernel(const float* __restrict__ z, int O,
                                                       float* __restrict__ out, int outBS, int c0) {
  int o = blockIdx.x;
  int tid = threadIdx.x;
  __shared__ float s1[256], s2[256];
  __shared__ float smv, srv;
  float a1 = 0.f, a2 = 0.f;
  for (int i = tid; i < BB * NN; i += 256) {
    int b = i >> 11, n = i & (NN - 1);
    float v = z[((size_t)b * O + o) * NN + n];
    a1 += v; a2 += v * v;
  }
  s1[tid] = a1; s2[tid] = a2;
  __syncthreads();
  for (int st = 128; st > 0; st >>= 1) {
    if (tid < st) { s1[tid] += s1[tid + st]; s2[tid] += s2[tid + st]; }
    __syncthreads();
  }
  if (tid == 0) {
    float m = s1[0] / (BB * NN);
    float var = s2[0] / (BB * NN) - m * m;
    smv = m; srv = rsqrtf(var + 1e-5f);
  }
  __syncthreads();
  float m = smv, r = srv;
  for (int i = tid; i < BB * NN; i += 256) {
    int b = i >> 11, n = i & (NN - 1);
    float v = (z[((size_t)b * O + o) * NN + n] - m) * r;
    out[(size_t)b * outBS + (c0 + o) * NN + n] = v >= 0.f ? v : 0.2f * v;
  }
}

// ---------------------------------------------------------------- fused BN+LReLU+max/mean pool (conv5)
// grid 1024 (o): stats over [B,N], then per-b max/mean of normalized values.
__global__ __launch_bounds__(256) void bn_pool_kernel(const float* __restrict__ z,
                                                      float* __restrict__ p) {
  int o = blockIdx.x;
  int tid = threadIdx.x;
  __shared__ float s1[256], s2[256];
  __shared__ float smv, srv;
  float a1 = 0.f, a2 = 0.f;
  for (int i = tid; i < BB * NN; i += 256) {
    int b = i >> 11, n = i & (NN - 1);
    float v = z[((size_t)b * 1024 + o) * NN + n];
    a1 += v; a2 += v * v;
  }
  s1[tid] = a1; s2[tid] = a2;
  __syncthreads();
  for (int st = 128; st > 0; st >>= 1) {
    if (tid < st) { s1[tid] += s1[tid + st]; s2[tid] += s2[tid + st]; }
    __syncthreads();
  }
  if (tid == 0) {
    float m = s1[0] / (BB * NN);
    float var = s2[0] / (BB * NN) - m * m;
    smv = m; srv = rsqrtf(var + 1e-5f);
  }
  __syncthreads();
  float m = smv, r = srv;
  // 32 threads per b
  int b = tid >> 5, l = tid & 31;
  const float* zp = z + ((size_t)b * 1024 + o) * NN;
  float mx = -INFINITY, sm = 0.f;
  for (int n = l; n < NN; n += 32) {
    float v = (zp[n] - m) * r;
    v = v >= 0.f ? v : 0.2f * v;
    mx = fmaxf(mx, v); sm += v;
  }
#pragma unroll
  for (int s = 16; s > 0; s >>= 1) {
    mx = fmaxf(mx, __shfl_xor(mx, s));
    sm += __shfl_xor(sm, s);
  }
  if (l == 0) {
    p[b * 2048 + o] = mx;
    p[b * 2048 + 1024 + o] = sm * (1.f / NN);
  }
}

__global__ __launch_bounds__(256) void copy_kernel(const float* __restrict__ x, int bs,
                                                   float* __restrict__ out, int outBS, int c0) {
  int n = blockIdx.x * blockDim.x + threadIdx.x;
  int c = blockIdx.y, b = blockIdx.z;
  out[(size_t)b * outBS + (c0 + c) * NN + n] = x[(size_t)b * bs + c * NN + n];
}

__global__ __launch_bounds__(64) void linear_kernel(const float* __restrict__ in, int IN, int OUT,
                                                    const float* __restrict__ w,
                                                    const float* __restrict__ bias,
                                                    float* __restrict__ out) {
  int o = blockIdx.x;
  int b = o / OUT, f = o % OUT;
  const float* ip = in + (size_t)b * IN;
  const float* wp = w + (size_t)f * IN;
  float a = 0.f;
  for (int i = threadIdx.x; i < IN; i += 64) a += ip[i] * wp[i];
#pragma unroll
  for (int s = 32; s > 0; s >>= 1) a += __shfl_down(a, s);
  if (threadIdx.x == 0) out[o] = a + bias[f];
}

__global__ __launch_bounds__(256) void bnf_kernel(float* __restrict__ t, int F) {
  int f = blockIdx.x * blockDim.x + threadIdx.x;
  if (f >= F) return;
  float s = 0.f, s2 = 0.f;
  for (int b = 0; b < BB; ++b) { float v = t[b * F + f]; s += v; s2 += v * v; }
  float m = s * (1.f / BB);
  float var = s2 * (1.f / BB) - m * m;
  float r = rsqrtf(var + 1e-5f);
  for (int b = 0; b < BB; ++b) {
    float v = (t[b * F + f] - m) * r;
    t[b * F + f] = v >= 0.f ? v : 0.2f * v;
  }
}

// ---------------------------------------------------------------- host side

struct SAW { const float *wq, *wk, *wv, *wc; };

static inline void run_conv(const float* in, int inBS, int C, int O, const float* w,
                            float* z, hipStream_t st) {
  if (O % 128 == 0)
    conv_gemm128_db_kernel<<<dim3(NN / 128, O / 128, BB), 256, 0, st>>>(in, inBS, C, O, w, z);
  else
    conv_gemm_kernel<<<dim3(NN / 64, (O + 63) / 64, BB), 256, 0, st>>>(in, inBS, C, O, w, z);
}

template <int C>
static inline void run_sa(const float* xin, int xbs, SAW w,
                          float* xT, float* U, float* UT, float* AGGt, float* AGG,
                          float* z, float* h, float* sq, int* idx,
                          float* M, float* D, int nb, hipStream_t st) {
  sq_kernel<<<BB * NN / 256, 256, 0, st>>>(xin, xbs, C, sq);
  transpose_kernel<<<dim3(NN / 32, (C + 31) / 32, BB), 256, 0, st>>>(xin, xbs, C, NN, xT);
  mprep_kernel<<<(C * C + 255) / 256, 256, 0, st>>>(w.wq, w.wk, C, M);
  for (int bb = 0; bb < BB; bb += nb) {
    pd_gemm128_db_kernel<<<dim3(NN / 128, NN / 128, nb), 256, 0, st>>>(xin, xbs, C, sq, D, bb);
    topk_kernel<<<dim3(NN, nb), 64, 0, st>>>(D, idx, bb);
  }
  run_conv(xin, xbs, C, C, M, U, st);                              // U = M . x  [C][N]
  transpose_kernel<<<dim3(NN / 32, (C + 31) / 32, BB), 256, 0, st>>>(U, C * NN, C, NN, UT);
  att_wave_kernel<C><<<BB * NN, 64, 0, st>>>(xT, UT, idx, AGGt);   // AGGt [N][C]
  transpose_kernel<<<dim3((C + 31) / 32, NN / 32, BB), 256, 0, st>>>(AGGt, NN * C, NN, C, AGG);
  run_conv(AGG, C * NN, C, C, w.wv, U, st);                        // V = wv . AGG (reuse U)
  run_conv(U, C * NN, C, C, w.wc, z, st);                          // Z = wc . V
  bn_fused_kernel<<<C, 256, 0, st>>>(z, C, h, 2 * C * NN, 0);
  copy_kernel<<<dim3(NN / 256, C, BB), 256, 0, st>>>(xin, xbs, h, 2 * C * NN, C);
}

static inline void run_conv_bn(const float* in, int inBS, int Cin, int O, const float* w,
                               float* z, float* out, int outBS, int c0, hipStream_t st) {
  run_conv(in, inBS, Cin, O, w, z, st);
  bn_fused_kernel<<<O, 256, 0, st>>>(z, O, out, outBS, c0);
}

extern "C" void kernel_launch(void* const* d_in, const int* in_sizes, int n_in,
                              void* d_out, int out_size, void* d_ws, size_t ws_size,
                              hipStream_t stream) {
  const float* x = (const float*)d_in[0];
  SAW sa1{(const float*)d_in[1], (const float*)d_in[2], (const float*)d_in[3], (const float*)d_in[4]};
  SAW sa2{(const float*)d_in[5], (const float*)d_in[6], (const float*)d_in[7], (const float*)d_in[8]};
  SAW sa3{(const float*)d_in[9], (const float*)d_in[10], (const float*)d_in[11], (const float*)d_in[12]};
  SAW sa4{(const float*)d_in[13], (const float*)d_in[14], (const float*)d_in[15], (const float*)d_in[16]};
  const float* conv1_w = (const float*)d_in[17];
  const float* conv2_w = (const float*)d_in[18];
  const float* conv3_w = (const float*)d_in[19];
  const float* conv4_w = (const float*)d_in[20];
  const float* conv5_w = (const float*)d_in[21];
  const float* lin1_w = (const float*)d_in[22];
  const float* lin1_b = (const float*)d_in[23];
  const float* lin2_w = (const float*)d_in[24];
  const float* lin2_b = (const float*)d_in[25];
  const float* lin3_w = (const float*)d_in[26];
  const float* lin3_b = (const float*)d_in[27];

  char* ws = (char*)d_ws;
  size_t off = 0;
  auto take = [&](size_t bytes) -> void* {
    void* p = ws + off;
    off += (bytes + 255) & ~(size_t)255;
    return p;
  };
  float* sq   = (float*)take((size_t)BB * NN * 4);
  int*   idx  = (int*)take((size_t)BB * NN * KNB * 4);
  float* M    = (float*)take((size_t)128 * 128 * 4);
  float* U    = (float*)take((size_t)BB * 128 * NN * 4);
  float* AGG  = (float*)take((size_t)BB * 128 * NN * 4);  // also hosts xT (disjoint lifetime)
  float* h    = (float*)take((size_t)BB * 256 * NN * 4);  // also hosts UT (disjoint lifetime)
  float* z    = (float*)take((size_t)BB * 1024 * NN * 4); // also hosts AGGt + per-batch D
  float* xc   = (float*)take((size_t)BB * 512 * NN * 4);
  float* p    = (float*)take((size_t)BB * 2048 * 4);
  float* t1   = (float*)take((size_t)BB * 512 * 4);
  float* t2   = (float*)take((size_t)BB * 256 * 4);
  (void)n_in; (void)in_sizes; (void)out_size;

  float* xT = AGG;
  float* UT = h;
  float* AGGt = z;

  size_t dfull = (size_t)BB * NN * NN * 4;
  bool fullD = (ws_size > off + dfull + 4096);
  float* D = fullD ? (float*)take(dfull) : z;
  int nbatch = fullD ? BB : 1;

  // SA1 (C=3) -> h [B,6,N]
  run_sa<3>(x, 3 * NN, sa1, xT, U, UT, AGGt, AGG, z, h, sq, idx, M, D, nbatch, stream);
  run_conv_bn(h, 6 * NN, 6, 64, conv1_w, z, xc, 512 * NN, 0, stream);
  // SA2 (C=64) on x1
  run_sa<64>(xc + 0 * NN, 512 * NN, sa2, xT, U, UT, AGGt, AGG, z, h, sq, idx, M, D, nbatch, stream);
  run_conv_bn(h, 128 * NN, 128, 64, conv2_w, z, xc, 512 * NN, 64, stream);
  // SA3 (C=64) on x2
  run_sa<64>(xc + 64 * NN, 512 * NN, sa3, xT, U, UT, AGGt, AGG, z, h, sq, idx, M, D, nbatch, stream);
  run_conv_bn(h, 128 * NN, 128, 128, conv3_w, z, xc, 512 * NN, 128, stream);
  // SA4 (C=128) on x3
  run_sa<128>(xc + 128 * NN, 512 * NN, sa4, xT, U, UT, AGGt, AGG, z, h, sq, idx, M, D, nbatch, stream);
  run_conv_bn(h, 256 * NN, 256, 256, conv4_w, z, xc, 512 * NN, 256, stream);
  // conv5: xc [B,512,N] -> z [B,1024,N]; BN+LReLU+pool fused -> p
  run_conv(xc, 512 * NN, 512, 1024, conv5_w, z, stream);
  bn_pool_kernel<<<1024, 256, 0, stream>>>(z, p);
  // FC head
  linear_kernel<<<BB * 512, 64, 0, stream>>>(p, 2048, 512, lin1_w, lin1_b, t1);
  bnf_kernel<<<2, 256, 0, stream>>>(t1, 512);
  linear_kernel<<<BB * 256, 64, 0, stream>>>(t1, 512, 256, lin2_w, lin2_b, t2);
  bnf_kernel<<<1, 256, 0, stream>>>(t2, 256);
  linear_kernel<<<BB * 40, 64, 0, stream>>>(t2, 256, 40, lin3_w, lin3_b, (float*)d_out);
}

// Round 7
// 2374.976 us; speedup vs baseline: 1.3872x; 1.3872x over previous
//
#include <hip/hip_runtime.h>
#include <math.h>

#define BB 8
#define NN 2048
#define KNB 20

// ---------------------------------------------------------------- sq
__global__ __launch_bounds__(256) void sq_kernel(const float* __restrict__ x, int bs, int C,
                                                 float* __restrict__ sq) {
  int t = blockIdx.x * blockDim.x + threadIdx.x;
  int b = t / NN, n = t % NN;
  const float* xp = x + (size_t)b * bs + n;
  float s = 0.f;
  for (int c = 0; c < C; ++c) { float v = xp[c * NN]; s += v * v; }
  sq[t] = s;
}

// ---------------------------------------------------------------- M = wk^T wq
__global__ __launch_bounds__(256) void mprep_kernel(const float* __restrict__ wq,
                                                    const float* __restrict__ wk, int C,
                                                    float* __restrict__ M) {
  int T = blockIdx.x * 256 + threadIdx.x;
  if (T >= C * C) return;
  int c = T / C, cp = T % C;
  float a = 0.f;
  for (int e = 0; e < C; ++e) a += wk[e * C + c] * wq[e * C + cp];
  M[c * C + cp] = a;
}

// ---------------------------------------------------------------- transpose
__global__ __launch_bounds__(256) void transpose_kernel(const float* __restrict__ in, int inBS,
                                                        int R, int Cl, float* __restrict__ out) {
  __shared__ float tile[32][33];
  int b = blockIdx.z;
  const float* ip = in + (size_t)b * inBS;
  float* op = out + (size_t)b * R * Cl;
  int c0 = blockIdx.x * 32, r0 = blockIdx.y * 32;
  int tx = threadIdx.x & 31, ty = threadIdx.x >> 5;
  for (int yy = ty; yy < 32; yy += 8) {
    int r = r0 + yy, c = c0 + tx;
    tile[yy][tx] = (r < R && c < Cl) ? ip[(size_t)r * Cl + c] : 0.f;
  }
  __syncthreads();
  for (int yy = ty; yy < 32; yy += 8) {
    int c = c0 + yy, r = r0 + tx;
    if (c < Cl && r < R) op[(size_t)c * R + r] = tile[tx][yy];
  }
}

// ---------------------------------------------------------------- pd GEMM 128-tile, double-buffered
// P[bl][n][m] = 2*sum_c x[c][n]*x[c][m] - sq[m]
// __launch_bounds__(256,2): VGPR cap 256 (~150 needed). (256,3) capped at 84
// and spilled the accumulators -> 1.5 GB scratch traffic per dispatch (r6).
__global__ __launch_bounds__(256, 2) void pd_gemm128_db_kernel(
    const float* __restrict__ x, int bs, int C, const float* __restrict__ sq,
    float* __restrict__ P, int b_base) {
  const int b = b_base + blockIdx.z;
  const int n0 = blockIdx.x * 128, m0 = blockIdx.y * 128;
  const int tid = threadIdx.x;
  const int tm = tid & 15, tn = tid >> 4;
  __shared__ float As[2][16][128], Bs[2][16][128];
  const float* xb = x + (size_t)b * bs;
  float acc[8][8];
#pragma unroll
  for (int i = 0; i < 8; ++i)
#pragma unroll
    for (int j = 0; j < 8; ++j) acc[i][j] = 0.f;

  float4 ara[2], arb[2];
  auto load_tile = [&](int k0) {
#pragma unroll
    for (int it = 0; it < 2; ++it) {
      int i = it * 256 + tid;
      int kc = i >> 5, c4 = i & 31;
      bool ok = (k0 + kc) < C;
      ara[it] = ok ? *(const float4*)&xb[(size_t)(k0 + kc) * NN + n0 + c4 * 4]
                   : make_float4(0.f, 0.f, 0.f, 0.f);
      arb[it] = ok ? *(const float4*)&xb[(size_t)(k0 + kc) * NN + m0 + c4 * 4]
                   : make_float4(0.f, 0.f, 0.f, 0.f);
    }
  };
  auto store_tile = [&](int buf) {
#pragma unroll
    for (int it = 0; it < 2; ++it) {
      int i = it * 256 + tid;
      int kc = i >> 5, c4 = i & 31;
      *(float4*)&As[buf][kc][c4 * 4] = ara[it];
      *(float4*)&Bs[buf][kc][c4 * 4] = arb[it];
    }
  };

  load_tile(0);
  store_tile(0);
  int cur = 0;
  for (int k0 = 0; k0 < C; k0 += 16) {
    bool more = (k0 + 16) < C;
    if (more) load_tile(k0 + 16);
    __syncthreads();
#pragma unroll
    for (int kc = 0; kc < 16; ++kc) {
      float4 a0 = *(const float4*)&As[cur][kc][tn * 4];
      float4 a1 = *(const float4*)&As[cur][kc][64 + tn * 4];
      float4 b0 = *(const float4*)&Bs[cur][kc][tm * 4];
      float4 b1 = *(const float4*)&Bs[cur][kc][64 + tm * 4];
      float ar[8] = {a0.x, a0.y, a0.z, a0.w, a1.x, a1.y, a1.z, a1.w};
      float br[8] = {b0.x, b0.y, b0.z, b0.w, b1.x, b1.y, b1.z, b1.w};
#pragma unroll
      for (int i = 0; i < 8; ++i)
#pragma unroll
        for (int j = 0; j < 8; ++j) acc[i][j] += ar[i] * br[j];
    }
    if (more) store_tile(cur ^ 1);
    cur ^= 1;
  }
  float4 sqa = *(const float4*)&sq[b * NN + m0 + tm * 4];
  float4 sqb = *(const float4*)&sq[b * NN + m0 + 64 + tm * 4];
#pragma unroll
  for (int h = 0; h < 2; ++h)
#pragma unroll
    for (int i = 0; i < 4; ++i) {
      int r = h * 4 + i;
      int nn = n0 + h * 64 + tn * 4 + i;
      float* prow = &P[((size_t)blockIdx.z * NN + nn) * NN + m0];
      float4 o0, o1;
      o0.x = 2.f * acc[r][0] - sqa.x; o0.y = 2.f * acc[r][1] - sqa.y;
      o0.z = 2.f * acc[r][2] - sqa.z; o0.w = 2.f * acc[r][3] - sqa.w;
      o1.x = 2.f * acc[r][4] - sqb.x; o1.y = 2.f * acc[r][5] - sqb.y;
      o1.z = 2.f * acc[r][6] - sqb.z; o1.w = 2.f * acc[r][7] - sqb.w;
      *(float4*)&prow[tm * 4] = o0;
      *(float4*)&prow[64 + tm * 4] = o1;
    }
}

// ---------------------------------------------------------------- one-wave top-20
__global__ __launch_bounds__(64) void topk_kernel(const float* __restrict__ P,
                                                  int* __restrict__ idx, int b_base) {
  const int n = blockIdx.x;
  const int bl = blockIdx.y;
  const int b = b_base + bl;
  const int lane = threadIdx.x;
  const float* row = P + ((size_t)bl * NN + n) * NN;
  const float4* rp = (const float4*)row;
  float v[32];
#pragma unroll
  for (int q = 0; q < 8; ++q) {
    float4 vv = rp[q * 64 + lane];
    int mb = q * 256 + lane * 4;
    v[q * 4 + 0] = (mb + 0 == n) ? -INFINITY : vv.x;
    v[q * 4 + 1] = (mb + 1 == n) ? -INFINITY : vv.y;
    v[q * 4 + 2] = (mb + 2 == n) ? -INFINITY : vv.z;
    v[q * 4 + 3] = (mb + 3 == n) ? -INFINITY : vv.w;
  }
  int* op = idx + (size_t)(b * NN + n) * KNB;
  for (int k = 0; k < KNB; ++k) {
    float bv = v[0]; int bj = 0;
#pragma unroll
    for (int j = 1; j < 32; ++j)
      if (v[j] > bv) { bv = v[j]; bj = j; }
    int bm = (bj >> 2) * 256 + lane * 4 + (bj & 3);
#pragma unroll
    for (int s = 32; s > 0; s >>= 1) {
      float ov = __shfl_down(bv, s);
      int om = __shfl_down(bm, s);
      if (ov > bv) { bv = ov; bm = om; }
    }
    bm = __shfl(bm, 0);
    if (lane == 0) op[k] = bm;
    if (((bm >> 2) & 63) == lane) {
      int jj = ((bm >> 8) << 2) | (bm & 3);
#pragma unroll
      for (int j = 0; j < 32; ++j)
        if (j == jj) v[j] = -INFINITY;
    }
  }
}

// ---------------------------------------------------------------- conv GEMM 64-tile (small O)
__global__ __launch_bounds__(256, 2) void conv_gemm_kernel(
    const float* __restrict__ in, int inBS, int C, int O,
    const float* __restrict__ w, float* __restrict__ z) {
  const int b = blockIdx.z;
  const int n0 = blockIdx.x * 64, o0 = blockIdx.y * 64;
  const int tid = threadIdx.x;
  const int tm = tid & 15, tn = tid >> 4;
  __shared__ float Ws[16][68];
  __shared__ float Xs[16][64];
  const float* ib = in + (size_t)b * inBS;
  float acc[4][4];
#pragma unroll
  for (int i = 0; i < 4; ++i)
#pragma unroll
    for (int j = 0; j < 4; ++j) acc[i][j] = 0.f;

  for (int k0 = 0; k0 < C; k0 += 16) {
    __syncthreads();
#pragma unroll
    for (int it = 0; it < 4; ++it) {
      int i = it * 256 + tid;
      int kc = i >> 6, nl = i & 63;
      Xs[kc][nl] = ((k0 + kc) < C) ? ib[(size_t)(k0 + kc) * NN + n0 + nl] : 0.f;
      int ol = i >> 4, kc2 = i & 15;
      Ws[kc2][ol] = ((o0 + ol) < O && (k0 + kc2) < C) ? w[(size_t)(o0 + ol) * C + k0 + kc2] : 0.f;
    }
    __syncthreads();
#pragma unroll
    for (int kc = 0; kc < 16; ++kc) {
      float4 a = *(const float4*)&Ws[kc][tn * 4];
      float4 bv = *(const float4*)&Xs[kc][tm * 4];
      acc[0][0] += a.x * bv.x; acc[0][1] += a.x * bv.y; acc[0][2] += a.x * bv.z; acc[0][3] += a.x * bv.w;
      acc[1][0] += a.y * bv.x; acc[1][1] += a.y * bv.y; acc[1][2] += a.y * bv.z; acc[1][3] += a.y * bv.w;
      acc[2][0] += a.z * bv.x; acc[2][1] += a.z * bv.y; acc[2][2] += a.z * bv.z; acc[2][3] += a.z * bv.w;
      acc[3][0] += a.w * bv.x; acc[3][1] += a.w * bv.y; acc[3][2] += a.w * bv.z; acc[3][3] += a.w * bv.w;
    }
  }
#pragma unroll
  for (int i = 0; i < 4; ++i) {
    int o = o0 + tn * 4 + i;
    if (o < O) {
      float4 ov;
      ov.x = acc[i][0]; ov.y = acc[i][1]; ov.z = acc[i][2]; ov.w = acc[i][3];
      *(float4*)&z[((size_t)b * O + o) * NN + n0 + tm * 4] = ov;
    }
  }
}

// ---------------------------------------------------------------- conv GEMM 128-tile, double-buffered
// __launch_bounds__(256,2): see pd kernel comment (r6 spill at (256,3)).
__global__ __launch_bounds__(256, 2) void conv_gemm128_db_kernel(
    const float* __restrict__ in, int inBS, int C, int O,
    const float* __restrict__ w, float* __restrict__ z) {
  const int b = blockIdx.z;
  const int n0 = blockIdx.x * 128, o0 = blockIdx.y * 128;
  const int tid = threadIdx.x;
  const int tm = tid & 15, tn = tid >> 4;
  __shared__ float Xs[2][16][128];
  __shared__ float Ws[2][16][132];
  const float* ib = in + (size_t)b * inBS;
  float acc[8][8];
#pragma unroll
  for (int i = 0; i < 8; ++i)
#pragma unroll
    for (int j = 0; j < 8; ++j) acc[i][j] = 0.f;

  float4 xr[2], wr[2];
  auto load_tile = [&](int k0) {
#pragma unroll
    for (int it = 0; it < 2; ++it) {
      int i = it * 256 + tid;
      int kc = i >> 5, c4 = i & 31;
      xr[it] = ((k0 + kc) < C) ? *(const float4*)&ib[(size_t)(k0 + kc) * NN + n0 + c4 * 4]
                               : make_float4(0.f, 0.f, 0.f, 0.f);
      int ol = i >> 2, kq = i & 3;
      wr[it] = ((k0 + kq * 4) < C) ? *(const float4*)&w[(size_t)(o0 + ol) * C + k0 + kq * 4]
                                   : make_float4(0.f, 0.f, 0.f, 0.f);
    }
  };
  auto store_tile = [&](int buf) {
#pragma unroll
    for (int it = 0; it < 2; ++it) {
      int i = it * 256 + tid;
      int kc = i >> 5, c4 = i & 31;
      *(float4*)&Xs[buf][kc][c4 * 4] = xr[it];
      int ol = i >> 2, kq = i & 3;
      Ws[buf][kq * 4 + 0][ol] = wr[it].x;
      Ws[buf][kq * 4 + 1][ol] = wr[it].y;
      Ws[buf][kq * 4 + 2][ol] = wr[it].z;
      Ws[buf][kq * 4 + 3][ol] = wr[it].w;
    }
  };

  load_tile(0);
  store_tile(0);
  int cur = 0;
  for (int k0 = 0; k0 < C; k0 += 16) {
    bool more = (k0 + 16) < C;
    if (more) load_tile(k0 + 16);
    __syncthreads();
#pragma unroll
    for (int kc = 0; kc < 16; ++kc) {
      float4 a0 = *(const float4*)&Ws[cur][kc][tn * 4];
      float4 a1 = *(const float4*)&Ws[cur][kc][64 + tn * 4];
      float4 b0 = *(const float4*)&Xs[cur][kc][tm * 4];
      float4 b1 = *(const float4*)&Xs[cur][kc][64 + tm * 4];
      float ar[8] = {a0.x, a0.y, a0.z, a0.w, a1.x, a1.y, a1.z, a1.w};
      float br[8] = {b0.x, b0.y, b0.z, b0.w, b1.x, b1.y, b1.z, b1.w};
#pragma unroll
      for (int i = 0; i < 8; ++i)
#pragma unroll
        for (int j = 0; j < 8; ++j) acc[i][j] += ar[i] * br[j];
    }
    if (more) store_tile(cur ^ 1);
    cur ^= 1;
  }
#pragma unroll
  for (int h = 0; h < 2; ++h)
#pragma unroll
    for (int i = 0; i < 4; ++i) {
      int r = h * 4 + i;
      int o = o0 + h * 64 + tn * 4 + i;
      float* zrow = &z[((size_t)b * O + o) * NN + n0];
      float4 o0v, o1v;
      o0v.x = acc[r][0]; o0v.y = acc[r][1]; o0v.z = acc[r][2]; o0v.w = acc[r][3];
      o1v.x = acc[r][4]; o1v.y = acc[r][5]; o1v.z = acc[r][6]; o1v.w = acc[r][7];
      *(float4*)&zrow[tm * 4] = o0v;
      *(float4*)&zrow[64 + tm * 4] = o1v;
    }
}

// ---------------------------------------------------------------- attention (wave/point)
template <int C>
__global__ __launch_bounds__(64) void att_wave_kernel(
    const float* __restrict__ xT, const float* __restrict__ UT,
    const int* __restrict__ idx, float* __restrict__ AGGt) {
  const int n = blockIdx.x & (NN - 1);
  const int b = blockIdx.x >> 11;
  const int lane = threadIdx.x;
  constexpr int CP = C + 1;
  __shared__ float nb[KNB][CP];
  __shared__ float sl[KNB];
  __shared__ int nidx[KNB];
  __shared__ float ul[C];
  const float* xTb = xT + (size_t)b * NN * C;
  if (lane < KNB) nidx[lane] = idx[(size_t)(b * NN + n) * KNB + lane];
  for (int c = lane; c < C; c += 64) ul[c] = UT[((size_t)b * NN + n) * C + c];
  __syncthreads();
  for (int i = lane; i < KNB * C; i += 64) {
    int k = i / C, c = i - k * C;
    nb[k][c] = xTb[(size_t)nidx[k] * C + c];
  }
  __syncthreads();
  float sv = -INFINITY;
  if (lane < KNB) {
    float a = 0.f;
#pragma unroll
    for (int c = 0; c < C; ++c) a += nb[lane][c] * ul[c];
    sv = a / sqrtf((float)C);
  }
  float mx = sv;
#pragma unroll
  for (int s = 32; s > 0; s >>= 1) mx = fmaxf(mx, __shfl_xor(mx, s));
  float e = (lane < KNB) ? expf(sv - mx) : 0.f;
  float sum = e;
#pragma unroll
  for (int s = 32; s > 0; s >>= 1) sum += __shfl_xor(sum, s);
  if (lane < KNB) sl[lane] = e / sum;
  __syncthreads();
  const float* xTn = xTb + (size_t)n * C;
  float* op = AGGt + ((size_t)b * NN + n) * C;
  for (int c = lane; c < C; c += 64) {
    float a = 0.f;
#pragma unroll
    for (int k = 0; k < KNB; ++k) a += sl[k] * nb[k][c];
    op[c] = a - xTn[c];
  }
}

// ---------------------------------------------------------------- fused BN (+LReLU)
__global__ __launch_bounds__(256) void bn_fused_kernel(const float* __restrict__ z, int O,
                                                       float* __restrict__ out, int outBS, int c0) {
  int o = blockIdx.x;
  int tid = threadIdx.x;
  __shared__ float s1[256], s2[256];
  __shared__ float smv, srv;
  float a1 = 0.f, a2 = 0.f;
  for (int i = tid; i < BB * NN; i += 256) {
    int b = i >> 11, n = i & (NN - 1);
    float v = z[((size_t)b * O + o) * NN + n];
    a1 += v; a2 += v * v;
  }
  s1[tid] = a1; s2[tid] = a2;
  __syncthreads();
  for (int st = 128; st > 0; st >>= 1) {
    if (tid < st) { s1[tid] += s1[tid + st]; s2[tid] += s2[tid + st]; }
    __syncthreads();
  }
  if (tid == 0) {
    float m = s1[0] / (BB * NN);
    float var = s2[0] / (BB * NN) - m * m;
    smv = m; srv = rsqrtf(var + 1e-5f);
  }
  __syncthreads();
  float m = smv, r = srv;
  for (int i = tid; i < BB * NN; i += 256) {
    int b = i >> 11, n = i & (NN - 1);
    float v = (z[((size_t)b * O + o) * NN + n] - m) * r;
    out[(size_t)b * outBS + (c0 + o) * NN + n] = v >= 0.f ? v : 0.2f * v;
  }
}

// ---------------------------------------------------------------- fused BN+LReLU+max/mean pool (conv5)
__global__ __launch_bounds__(256) void bn_pool_kernel(const float* __restrict__ z,
                                                      float* __restrict__ p) {
  int o = blockIdx.x;
  int tid = threadIdx.x;
  __shared__ float s1[256], s2[256];
  __shared__ float smv, srv;
  float a1 = 0.f, a2 = 0.f;
  for (int i = tid; i < BB * NN; i += 256) {
    int b = i >> 11, n = i & (NN - 1);
    float v = z[((size_t)b * 1024 + o) * NN + n];
    a1 += v; a2 += v * v;
  }
  s1[tid] = a1; s2[tid] = a2;
  __syncthreads();
  for (int st = 128; st > 0; st >>= 1) {
    if (tid < st) { s1[tid] += s1[tid + st]; s2[tid] += s2[tid + st]; }
    __syncthreads();
  }
  if (tid == 0) {
    float m = s1[0] / (BB * NN);
    float var = s2[0] / (BB * NN) - m * m;
    smv = m; srv = rsqrtf(var + 1e-5f);
  }
  __syncthreads();
  float m = smv, r = srv;
  int b = tid >> 5, l = tid & 31;
  const float* zp = z + ((size_t)b * 1024 + o) * NN;
  float mx = -INFINITY, sm = 0.f;
  for (int n = l; n < NN; n += 32) {
    float v = (zp[n] - m) * r;
    v = v >= 0.f ? v : 0.2f * v;
    mx = fmaxf(mx, v); sm += v;
  }
#pragma unroll
  for (int s = 16; s > 0; s >>= 1) {
    mx = fmaxf(mx, __shfl_xor(mx, s));
    sm += __shfl_xor(sm, s);
  }
  if (l == 0) {
    p[b * 2048 + o] = mx;
    p[b * 2048 + 1024 + o] = sm * (1.f / NN);
  }
}

__global__ __launch_bounds__(256) void copy_kernel(const float* __restrict__ x, int bs,
                                                   float* __restrict__ out, int outBS, int c0) {
  int n = blockIdx.x * blockDim.x + threadIdx.x;
  int c = blockIdx.y, b = blockIdx.z;
  out[(size_t)b * outBS + (c0 + c) * NN + n] = x[(size_t)b * bs + c * NN + n];
}

__global__ __launch_bounds__(64) void linear_kernel(const float* __restrict__ in, int IN, int OUT,
                                                    const float* __restrict__ w,
                                                    const float* __restrict__ bias,
                                                    float* __restrict__ out) {
  int o = blockIdx.x;
  int b = o / OUT, f = o % OUT;
  const float* ip = in + (size_t)b * IN;
  const float* wp = w + (size_t)f * IN;
  float a = 0.f;
  for (int i = threadIdx.x; i < IN; i += 64) a += ip[i] * wp[i];
#pragma unroll
  for (int s = 32; s > 0; s >>= 1) a += __shfl_down(a, s);
  if (threadIdx.x == 0) out[o] = a + bias[f];
}

__global__ __launch_bounds__(256) void bnf_kernel(float* __restrict__ t, int F) {
  int f = blockIdx.x * blockDim.x + threadIdx.x;
  if (f >= F) return;
  float s = 0.f, s2 = 0.f;
  for (int b = 0; b < BB; ++b) { float v = t[b * F + f]; s += v; s2 += v * v; }
  float m = s * (1.f / BB);
  float var = s2 * (1.f / BB) - m * m;
  float r = rsqrtf(var + 1e-5f);
  for (int b = 0; b < BB; ++b) {
    float v = (t[b * F + f] - m) * r;
    t[b * F + f] = v >= 0.f ? v : 0.2f * v;
  }
}

// ---------------------------------------------------------------- host side

struct SAW { const float *wq, *wk, *wv, *wc; };

static inline void run_conv(const float* in, int inBS, int C, int O, const float* w,
                            float* z, hipStream_t st) {
  if (O % 128 == 0)
    conv_gemm128_db_kernel<<<dim3(NN / 128, O / 128, BB), 256, 0, st>>>(in, inBS, C, O, w, z);
  else
    conv_gemm_kernel<<<dim3(NN / 64, (O + 63) / 64, BB), 256, 0, st>>>(in, inBS, C, O, w, z);
}

template <int C>
static inline void run_sa(const float* xin, int xbs, SAW w,
                          float* xT, float* U, float* UT, float* AGGt, float* AGG,
                          float* z, float* h, float* sq, int* idx,
                          float* M, float* D, int nb, hipStream_t st) {
  sq_kernel<<<BB * NN / 256, 256, 0, st>>>(xin, xbs, C, sq);
  transpose_kernel<<<dim3(NN / 32, (C + 31) / 32, BB), 256, 0, st>>>(xin, xbs, C, NN, xT);
  mprep_kernel<<<(C * C + 255) / 256, 256, 0, st>>>(w.wq, w.wk, C, M);
  for (int bb = 0; bb < BB; bb += nb) {
    pd_gemm128_db_kernel<<<dim3(NN / 128, NN / 128, nb), 256, 0, st>>>(xin, xbs, C, sq, D, bb);
    topk_kernel<<<dim3(NN, nb), 64, 0, st>>>(D, idx, bb);
  }
  run_conv(xin, xbs, C, C, M, U, st);                              // U = M . x  [C][N]
  transpose_kernel<<<dim3(NN / 32, (C + 31) / 32, BB), 256, 0, st>>>(U, C * NN, C, NN, UT);
  att_wave_kernel<C><<<BB * NN, 64, 0, st>>>(xT, UT, idx, AGGt);   // AGGt [N][C]
  transpose_kernel<<<dim3((C + 31) / 32, NN / 32, BB), 256, 0, st>>>(AGGt, NN * C, NN, C, AGG);
  run_conv(AGG, C * NN, C, C, w.wv, U, st);                        // V = wv . AGG (reuse U)
  run_conv(U, C * NN, C, C, w.wc, z, st);                          // Z = wc . V
  bn_fused_kernel<<<C, 256, 0, st>>>(z, C, h, 2 * C * NN, 0);
  copy_kernel<<<dim3(NN / 256, C, BB), 256, 0, st>>>(xin, xbs, h, 2 * C * NN, C);
}

static inline void run_conv_bn(const float* in, int inBS, int Cin, int O, const float* w,
                               float* z, float* out, int outBS, int c0, hipStream_t st) {
  run_conv(in, inBS, Cin, O, w, z, st);
  bn_fused_kernel<<<O, 256, 0, st>>>(z, O, out, outBS, c0);
}

extern "C" void kernel_launch(void* const* d_in, const int* in_sizes, int n_in,
                              void* d_out, int out_size, void* d_ws, size_t ws_size,
                              hipStream_t stream) {
  const float* x = (const float*)d_in[0];
  SAW sa1{(const float*)d_in[1], (const float*)d_in[2], (const float*)d_in[3], (const float*)d_in[4]};
  SAW sa2{(const float*)d_in[5], (const float*)d_in[6], (const float*)d_in[7], (const float*)d_in[8]};
  SAW sa3{(const float*)d_in[9], (const float*)d_in[10], (const float*)d_in[11], (const float*)d_in[12]};
  SAW sa4{(const float*)d_in[13], (const float*)d_in[14], (const float*)d_in[15], (const float*)d_in[16]};
  const float* conv1_w = (const float*)d_in[17];
  const float* conv2_w = (const float*)d_in[18];
  const float* conv3_w = (const float*)d_in[19];
  const float* conv4_w = (const float*)d_in[20];
  const float* conv5_w = (const float*)d_in[21];
  const float* lin1_w = (const float*)d_in[22];
  const float* lin1_b = (const float*)d_in[23];
  const float* lin2_w = (const float*)d_in[24];
  const float* lin2_b = (const float*)d_in[25];
  const float* lin3_w = (const float*)d_in[26];
  const float* lin3_b = (const float*)d_in[27];

  char* ws = (char*)d_ws;
  size_t off = 0;
  auto take = [&](size_t bytes) -> void* {
    void* p = ws + off;
    off += (bytes + 255) & ~(size_t)255;
    return p;
  };
  float* sq   = (float*)take((size_t)BB * NN * 4);
  int*   idx  = (int*)take((size_t)BB * NN * KNB * 4);
  float* M    = (float*)take((size_t)128 * 128 * 4);
  float* U    = (float*)take((size_t)BB * 128 * NN * 4);
  float* AGG  = (float*)take((size_t)BB * 128 * NN * 4);  // also hosts xT (disjoint lifetime)
  float* h    = (float*)take((size_t)BB * 256 * NN * 4);  // also hosts UT (disjoint lifetime)
  float* z    = (float*)take((size_t)BB * 1024 * NN * 4); // also hosts AGGt + per-batch D
  float* xc   = (float*)take((size_t)BB * 512 * NN * 4);
  float* p    = (float*)take((size_t)BB * 2048 * 4);
  float* t1   = (float*)take((size_t)BB * 512 * 4);
  float* t2   = (float*)take((size_t)BB * 256 * 4);
  (void)n_in; (void)in_sizes; (void)out_size;

  float* xT = AGG;
  float* UT = h;
  float* AGGt = z;

  size_t dfull = (size_t)BB * NN * NN * 4;
  bool fullD = (ws_size > off + dfull + 4096);
  float* D = fullD ? (float*)take(dfull) : z;
  int nbatch = fullD ? BB : 1;

  // SA1 (C=3) -> h [B,6,N]
  run_sa<3>(x, 3 * NN, sa1, xT, U, UT, AGGt, AGG, z, h, sq, idx, M, D, nbatch, stream);
  run_conv_bn(h, 6 * NN, 6, 64, conv1_w, z, xc, 512 * NN, 0, stream);
  // SA2 (C=64) on x1
  run_sa<64>(xc + 0 * NN, 512 * NN, sa2, xT, U, UT, AGGt, AGG, z, h, sq, idx, M, D, nbatch, stream);
  run_conv_bn(h, 128 * NN, 128, 64, conv2_w, z, xc, 512 * NN, 64, stream);
  // SA3 (C=64) on x2
  run_sa<64>(xc + 64 * NN, 512 * NN, sa3, xT, U, UT, AGGt, AGG, z, h, sq, idx, M, D, nbatch, stream);
  run_conv_bn(h, 128 * NN, 128, 128, conv3_w, z, xc, 512 * NN, 128, stream);
  // SA4 (C=128) on x3
  run_sa<128>(xc + 128 * NN, 512 * NN, sa4, xT, U, UT, AGGt, AGG, z, h, sq, idx, M, D, nbatch, stream);
  run_conv_bn(h, 256 * NN, 256, 256, conv4_w, z, xc, 512 * NN, 256, stream);
  // conv5: xc [B,512,N] -> z [B,1024,N]; BN+LReLU+pool fused -> p
  run_conv(xc, 512 * NN, 512, 1024, conv5_w, z, stream);
  bn_pool_kernel<<<1024, 256, 0, stream>>>(z, p);
  // FC head
  linear_kernel<<<BB * 512, 64, 0, stream>>>(p, 2048, 512, lin1_w, lin1_b, t1);
  bnf_kernel<<<2, 256, 0, stream>>>(t1, 512);
  linear_kernel<<<BB * 256, 64, 0, stream>>>(t1, 512, 256, lin2_w, lin2_b, t2);
  bnf_kernel<<<1, 256, 0, stream>>>(t2, 256);
  linear_kernel<<<BB * 40, 64, 0, stream>>>(t2, 256, 40, lin3_w, lin3_b, (float*)d_out);
}

// Round 8
// 1838.288 us; speedup vs baseline: 1.7922x; 1.2920x over previous
//
#include <hip/hip_runtime.h>
#include <math.h>

#define BB 8
#define NN 2048
#define KNB 20

typedef __attribute__((ext_vector_type(8))) short bf16x8;
typedef __attribute__((ext_vector_type(4))) float f32x4;

__device__ inline unsigned short f2bf(float f) {
  union { float f; unsigned u; } v; v.f = f;
  unsigned r = v.u + 0x7FFF + ((v.u >> 16) & 1);  // RNE
  return (unsigned short)(r >> 16);
}

// ---------------------------------------------------------------- sq
__global__ __launch_bounds__(256) void sq_kernel(const float* __restrict__ x, int bs, int C,
                                                 float* __restrict__ sq) {
  int t = blockIdx.x * blockDim.x + threadIdx.x;
  int b = t / NN, n = t % NN;
  const float* xp = x + (size_t)b * bs + n;
  float s = 0.f;
  for (int c = 0; c < C; ++c) { float v = xp[c * NN]; s += v * v; }
  sq[t] = s;
}

// ---------------------------------------------------------------- M = wk^T wq
__global__ __launch_bounds__(256) void mprep_kernel(const float* __restrict__ wq,
                                                    const float* __restrict__ wk, int C,
                                                    float* __restrict__ M) {
  int T = blockIdx.x * 256 + threadIdx.x;
  if (T >= C * C) return;
  int c = T / C, cp = T % C;
  float a = 0.f;
  for (int e = 0; e < C; ++e) a += wk[e * C + c] * wq[e * C + cp];
  M[c * C + cp] = a;
}

// ---------------------------------------------------------------- wcv = wc @ wv
__global__ __launch_bounds__(256) void wcv_kernel(const float* __restrict__ wc,
                                                  const float* __restrict__ wv, int C,
                                                  float* __restrict__ out) {
  int T = blockIdx.x * 256 + threadIdx.x;
  if (T >= C * C) return;
  int o = T / C, c = T % C;
  float a = 0.f;
  for (int e = 0; e < C; ++e) a += wc[o * C + e] * wv[e * C + c];
  out[o * C + c] = a;
}

// ---------------------------------------------------------------- converts
__global__ __launch_bounds__(256) void convert_bf16_kernel(const float* __restrict__ in,
                                                           unsigned short* __restrict__ out,
                                                           int count) {
  int i = blockIdx.x * 256 + threadIdx.x;
  if (i < count) out[i] = f2bf(in[i]);
}

// ---------------------------------------------------------------- transpose (fp32)
__global__ __launch_bounds__(256) void transpose_kernel(const float* __restrict__ in, int inBS,
                                                        int R, int Cl, float* __restrict__ out) {
  __shared__ float tile[32][33];
  int b = blockIdx.z;
  const float* ip = in + (size_t)b * inBS;
  float* op = out + (size_t)b * R * Cl;
  int c0 = blockIdx.x * 32, r0 = blockIdx.y * 32;
  int tx = threadIdx.x & 31, ty = threadIdx.x >> 5;
  for (int yy = ty; yy < 32; yy += 8) {
    int r = r0 + yy, c = c0 + tx;
    tile[yy][tx] = (r < R && c < Cl) ? ip[(size_t)r * Cl + c] : 0.f;
  }
  __syncthreads();
  for (int yy = ty; yy < 32; yy += 8) {
    int c = c0 + yy, r = r0 + tx;
    if (c < Cl && r < R) op[(size_t)c * R + r] = tile[tx][yy];
  }
}

// ---------------------------------------------------------------- transpose + bf16 convert
__global__ __launch_bounds__(256) void transpose_bf16_kernel(const float* __restrict__ in, int inBS,
                                                             int R, int Cl,
                                                             unsigned short* __restrict__ out) {
  __shared__ float tile[32][33];
  int b = blockIdx.z;
  const float* ip = in + (size_t)b * inBS;
  unsigned short* op = out + (size_t)b * R * Cl;
  int c0 = blockIdx.x * 32, r0 = blockIdx.y * 32;
  int tx = threadIdx.x & 31, ty = threadIdx.x >> 5;
  for (int yy = ty; yy < 32; yy += 8) {
    int r = r0 + yy, c = c0 + tx;
    tile[yy][tx] = (r < R && c < Cl) ? ip[(size_t)r * Cl + c] : 0.f;
  }
  __syncthreads();
  for (int yy = ty; yy < 32; yy += 8) {
    int c = c0 + yy, r = r0 + tx;
    if (c < Cl && r < R) op[(size_t)c * R + r] = f2bf(tile[tx][yy]);
  }
}

// ---------------------------------------------------------------- MFMA GEMM (LDS-free, L2-streamed)
// Z[b][o][n] = sum_k A[o][k] * B[b][n][k]; A,B bf16, Z fp32.
// Wave tile 32o x 64n via 8x mfma 16x16x32; block = 4 waves = 64o x 128n.
// A-frag: m=lane&15, k=quad*8+j ; B-frag: n=lane&15, k=quad*8+j ;
// D: col(n)=lane&15, row(m)=quad*4+reg.  O%64==0, N%128==0, K%32==0.
__global__ __launch_bounds__(256, 4) void mfma_gemm_kernel(
    const unsigned short* __restrict__ A, const unsigned short* __restrict__ B,
    float* __restrict__ Z, int O, int K) {
  const int b = blockIdx.z;
  const int n0 = blockIdx.x * 128, o0 = blockIdx.y * 64;
  const int wave = threadIdx.x >> 6, lane = threadIdx.x & 63;
  const int ow = o0 + (wave >> 1) * 32;
  const int nw = n0 + (wave & 1) * 64;
  const int l16 = lane & 15, q = lane >> 4;
  const unsigned short* Ap = A + (size_t)(ow + l16) * K + q * 8;
  const unsigned short* Bp = B + (size_t)b * NN * K + (size_t)(nw + l16) * K + q * 8;
  f32x4 acc[2][4];
#pragma unroll
  for (int s = 0; s < 2; ++s)
#pragma unroll
    for (int t = 0; t < 4; ++t) acc[s][t] = (f32x4){0.f, 0.f, 0.f, 0.f};

  for (int k0 = 0; k0 < K; k0 += 32) {
    bf16x8 a[2], bb[4];
#pragma unroll
    for (int s = 0; s < 2; ++s) a[s] = *(const bf16x8*)(Ap + (size_t)s * 16 * K + k0);
#pragma unroll
    for (int t = 0; t < 4; ++t) bb[t] = *(const bf16x8*)(Bp + (size_t)t * 16 * K + k0);
#pragma unroll
    for (int s = 0; s < 2; ++s)
#pragma unroll
      for (int t = 0; t < 4; ++t)
        acc[s][t] = __builtin_amdgcn_mfma_f32_16x16x32_bf16(a[s], bb[t], acc[s][t], 0, 0, 0);
  }
#pragma unroll
  for (int s = 0; s < 2; ++s)
#pragma unroll
    for (int t = 0; t < 4; ++t) {
      float* zp = Z + ((size_t)b * O + ow + s * 16 + q * 4) * NN + nw + t * 16 + l16;
#pragma unroll
      for (int r = 0; r < 4; ++r) zp[(size_t)r * NN] = acc[s][t][r];
    }
}

// ---------------------------------------------------------------- pd GEMM 128-tile, double-buffered
// __launch_bounds__(256,2): (256,3) capped VGPR at 84 and spilled (r6).
__global__ __launch_bounds__(256, 2) void pd_gemm128_db_kernel(
    const float* __restrict__ x, int bs, int C, const float* __restrict__ sq,
    float* __restrict__ P, int b_base) {
  const int b = b_base + blockIdx.z;
  const int n0 = blockIdx.x * 128, m0 = blockIdx.y * 128;
  const int tid = threadIdx.x;
  const int tm = tid & 15, tn = tid >> 4;
  __shared__ float As[2][16][128], Bs[2][16][128];
  const float* xb = x + (size_t)b * bs;
  float acc[8][8];
#pragma unroll
  for (int i = 0; i < 8; ++i)
#pragma unroll
    for (int j = 0; j < 8; ++j) acc[i][j] = 0.f;

  float4 ara[2], arb[2];
  auto load_tile = [&](int k0) {
#pragma unroll
    for (int it = 0; it < 2; ++it) {
      int i = it * 256 + tid;
      int kc = i >> 5, c4 = i & 31;
      bool ok = (k0 + kc) < C;
      ara[it] = ok ? *(const float4*)&xb[(size_t)(k0 + kc) * NN + n0 + c4 * 4]
                   : make_float4(0.f, 0.f, 0.f, 0.f);
      arb[it] = ok ? *(const float4*)&xb[(size_t)(k0 + kc) * NN + m0 + c4 * 4]
                   : make_float4(0.f, 0.f, 0.f, 0.f);
    }
  };
  auto store_tile = [&](int buf) {
#pragma unroll
    for (int it = 0; it < 2; ++it) {
      int i = it * 256 + tid;
      int kc = i >> 5, c4 = i & 31;
      *(float4*)&As[buf][kc][c4 * 4] = ara[it];
      *(float4*)&Bs[buf][kc][c4 * 4] = arb[it];
    }
  };

  load_tile(0);
  store_tile(0);
  int cur = 0;
  for (int k0 = 0; k0 < C; k0 += 16) {
    bool more = (k0 + 16) < C;
    if (more) load_tile(k0 + 16);
    __syncthreads();
#pragma unroll
    for (int kc = 0; kc < 16; ++kc) {
      float4 a0 = *(const float4*)&As[cur][kc][tn * 4];
      float4 a1 = *(const float4*)&As[cur][kc][64 + tn * 4];
      float4 b0 = *(const float4*)&Bs[cur][kc][tm * 4];
      float4 b1 = *(const float4*)&Bs[cur][kc][64 + tm * 4];
      float ar[8] = {a0.x, a0.y, a0.z, a0.w, a1.x, a1.y, a1.z, a1.w};
      float br[8] = {b0.x, b0.y, b0.z, b0.w, b1.x, b1.y, b1.z, b1.w};
#pragma unroll
      for (int i = 0; i < 8; ++i)
#pragma unroll
        for (int j = 0; j < 8; ++j) acc[i][j] += ar[i] * br[j];
    }
    if (more) store_tile(cur ^ 1);
    cur ^= 1;
  }
  float4 sqa = *(const float4*)&sq[b * NN + m0 + tm * 4];
  float4 sqb = *(const float4*)&sq[b * NN + m0 + 64 + tm * 4];
#pragma unroll
  for (int h = 0; h < 2; ++h)
#pragma unroll
    for (int i = 0; i < 4; ++i) {
      int r = h * 4 + i;
      int nn = n0 + h * 64 + tn * 4 + i;
      float* prow = &P[((size_t)blockIdx.z * NN + nn) * NN + m0];
      float4 o0, o1;
      o0.x = 2.f * acc[r][0] - sqa.x; o0.y = 2.f * acc[r][1] - sqa.y;
      o0.z = 2.f * acc[r][2] - sqa.z; o0.w = 2.f * acc[r][3] - sqa.w;
      o1.x = 2.f * acc[r][4] - sqb.x; o1.y = 2.f * acc[r][5] - sqb.y;
      o1.z = 2.f * acc[r][6] - sqb.z; o1.w = 2.f * acc[r][7] - sqb.w;
      *(float4*)&prow[tm * 4] = o0;
      *(float4*)&prow[64 + tm * 4] = o1;
    }
}

// ---------------------------------------------------------------- one-wave top-20
__global__ __launch_bounds__(64) void topk_kernel(const float* __restrict__ P,
                                                  int* __restrict__ idx, int b_base) {
  const int n = blockIdx.x;
  const int bl = blockIdx.y;
  const int b = b_base + bl;
  const int lane = threadIdx.x;
  const float* row = P + ((size_t)bl * NN + n) * NN;
  const float4* rp = (const float4*)row;
  float v[32];
#pragma unroll
  for (int qq = 0; qq < 8; ++qq) {
    float4 vv = rp[qq * 64 + lane];
    int mb = qq * 256 + lane * 4;
    v[qq * 4 + 0] = (mb + 0 == n) ? -INFINITY : vv.x;
    v[qq * 4 + 1] = (mb + 1 == n) ? -INFINITY : vv.y;
    v[qq * 4 + 2] = (mb + 2 == n) ? -INFINITY : vv.z;
    v[qq * 4 + 3] = (mb + 3 == n) ? -INFINITY : vv.w;
  }
  int* op = idx + (size_t)(b * NN + n) * KNB;
  for (int k = 0; k < KNB; ++k) {
    float bv = v[0]; int bj = 0;
#pragma unroll
    for (int j = 1; j < 32; ++j)
      if (v[j] > bv) { bv = v[j]; bj = j; }
    int bm = (bj >> 2) * 256 + lane * 4 + (bj & 3);
#pragma unroll
    for (int s = 32; s > 0; s >>= 1) {
      float ov = __shfl_down(bv, s);
      int om = __shfl_down(bm, s);
      if (ov > bv) { bv = ov; bm = om; }
    }
    bm = __shfl(bm, 0);
    if (lane == 0) op[k] = bm;
    if (((bm >> 2) & 63) == lane) {
      int jj = ((bm >> 8) << 2) | (bm & 3);
#pragma unroll
      for (int j = 0; j < 32; ++j)
        if (j == jj) v[j] = -INFINITY;
    }
  }
}

// ---------------------------------------------------------------- conv GEMM 64-tile (small O)
__global__ __launch_bounds__(256, 2) void conv_gemm_kernel(
    const float* __restrict__ in, int inBS, int C, int O,
    const float* __restrict__ w, float* __restrict__ z) {
  const int b = blockIdx.z;
  const int n0 = blockIdx.x * 64, o0 = blockIdx.y * 64;
  const int tid = threadIdx.x;
  const int tm = tid & 15, tn = tid >> 4;
  __shared__ float Ws[16][68];
  __shared__ float Xs[16][64];
  const float* ib = in + (size_t)b * inBS;
  float acc[4][4];
#pragma unroll
  for (int i = 0; i < 4; ++i)
#pragma unroll
    for (int j = 0; j < 4; ++j) acc[i][j] = 0.f;

  for (int k0 = 0; k0 < C; k0 += 16) {
    __syncthreads();
#pragma unroll
    for (int it = 0; it < 4; ++it) {
      int i = it * 256 + tid;
      int kc = i >> 6, nl = i & 63;
      Xs[kc][nl] = ((k0 + kc) < C) ? ib[(size_t)(k0 + kc) * NN + n0 + nl] : 0.f;
      int ol = i >> 4, kc2 = i & 15;
      Ws[kc2][ol] = ((o0 + ol) < O && (k0 + kc2) < C) ? w[(size_t)(o0 + ol) * C + k0 + kc2] : 0.f;
    }
    __syncthreads();
#pragma unroll
    for (int kc = 0; kc < 16; ++kc) {
      float4 a = *(const float4*)&Ws[kc][tn * 4];
      float4 bv = *(const float4*)&Xs[kc][tm * 4];
      acc[0][0] += a.x * bv.x; acc[0][1] += a.x * bv.y; acc[0][2] += a.x * bv.z; acc[0][3] += a.x * bv.w;
      acc[1][0] += a.y * bv.x; acc[1][1] += a.y * bv.y; acc[1][2] += a.y * bv.z; acc[1][3] += a.y * bv.w;
      acc[2][0] += a.z * bv.x; acc[2][1] += a.z * bv.y; acc[2][2] += a.z * bv.z; acc[2][3] += a.z * bv.w;
      acc[3][0] += a.w * bv.x; acc[3][1] += a.w * bv.y; acc[3][2] += a.w * bv.z; acc[3][3] += a.w * bv.w;
    }
  }
#pragma unroll
  for (int i = 0; i < 4; ++i) {
    int o = o0 + tn * 4 + i;
    if (o < O) {
      float4 ov;
      ov.x = acc[i][0]; ov.y = acc[i][1]; ov.z = acc[i][2]; ov.w = acc[i][3];
      *(float4*)&z[((size_t)b * O + o) * NN + n0 + tm * 4] = ov;
    }
  }
}

// ---------------------------------------------------------------- conv GEMM 128-tile, double-buffered
__global__ __launch_bounds__(256, 2) void conv_gemm128_db_kernel(
    const float* __restrict__ in, int inBS, int C, int O,
    const float* __restrict__ w, float* __restrict__ z) {
  const int b = blockIdx.z;
  const int n0 = blockIdx.x * 128, o0 = blockIdx.y * 128;
  const int tid = threadIdx.x;
  const int tm = tid & 15, tn = tid >> 4;
  __shared__ float Xs[2][16][128];
  __shared__ float Ws[2][16][132];
  const float* ib = in + (size_t)b * inBS;
  float acc[8][8];
#pragma unroll
  for (int i = 0; i < 8; ++i)
#pragma unroll
    for (int j = 0; j < 8; ++j) acc[i][j] = 0.f;

  float4 xr[2], wr[2];
  auto load_tile = [&](int k0) {
#pragma unroll
    for (int it = 0; it < 2; ++it) {
      int i = it * 256 + tid;
      int kc = i >> 5, c4 = i & 31;
      xr[it] = ((k0 + kc) < C) ? *(const float4*)&ib[(size_t)(k0 + kc) * NN + n0 + c4 * 4]
                               : make_float4(0.f, 0.f, 0.f, 0.f);
      int ol = i >> 2, kq = i & 3;
      wr[it] = ((k0 + kq * 4) < C) ? *(const float4*)&w[(size_t)(o0 + ol) * C + k0 + kq * 4]
                                   : make_float4(0.f, 0.f, 0.f, 0.f);
    }
  };
  auto store_tile = [&](int buf) {
#pragma unroll
    for (int it = 0; it < 2; ++it) {
      int i = it * 256 + tid;
      int kc = i >> 5, c4 = i & 31;
      *(float4*)&Xs[buf][kc][c4 * 4] = xr[it];
      int ol = i >> 2, kq = i & 3;
      Ws[buf][kq * 4 + 0][ol] = wr[it].x;
      Ws[buf][kq * 4 + 1][ol] = wr[it].y;
      Ws[buf][kq * 4 + 2][ol] = wr[it].z;
      Ws[buf][kq * 4 + 3][ol] = wr[it].w;
    }
  };

  load_tile(0);
  store_tile(0);
  int cur = 0;
  for (int k0 = 0; k0 < C; k0 += 16) {
    bool more = (k0 + 16) < C;
    if (more) load_tile(k0 + 16);
    __syncthreads();
#pragma unroll
    for (int kc = 0; kc < 16; ++kc) {
      float4 a0 = *(const float4*)&Ws[cur][kc][tn * 4];
      float4 a1 = *(const float4*)&Ws[cur][kc][64 + tn * 4];
      float4 b0 = *(const float4*)&Xs[cur][kc][tm * 4];
      float4 b1 = *(const float4*)&Xs[cur][kc][64 + tm * 4];
      float ar[8] = {a0.x, a0.y, a0.z, a0.w, a1.x, a1.y, a1.z, a1.w};
      float br[8] = {b0.x, b0.y, b0.z, b0.w, b1.x, b1.y, b1.z, b1.w};
#pragma unroll
      for (int i = 0; i < 8; ++i)
#pragma unroll
        for (int j = 0; j < 8; ++j) acc[i][j] += ar[i] * br[j];
    }
    if (more) store_tile(cur ^ 1);
    cur ^= 1;
  }
#pragma unroll
  for (int h = 0; h < 2; ++h)
#pragma unroll
    for (int i = 0; i < 4; ++i) {
      int r = h * 4 + i;
      int o = o0 + h * 64 + tn * 4 + i;
      float* zrow = &z[((size_t)b * O + o) * NN + n0];
      float4 o0v, o1v;
      o0v.x = acc[r][0]; o0v.y = acc[r][1]; o0v.z = acc[r][2]; o0v.w = acc[r][3];
      o1v.x = acc[r][4]; o1v.y = acc[r][5]; o1v.z = acc[r][6]; o1v.w = acc[r][7];
      *(float4*)&zrow[tm * 4] = o0v;
      *(float4*)&zrow[64 + tm * 4] = o1v;
    }
}

// ---------------------------------------------------------------- attention (wave/point)
template <int C>
__global__ __launch_bounds__(64) void att_wave_kernel(
    const float* __restrict__ xT, const float* __restrict__ UT,
    const int* __restrict__ idx, float* __restrict__ AGGt) {
  const int n = blockIdx.x & (NN - 1);
  const int b = blockIdx.x >> 11;
  const int lane = threadIdx.x;
  constexpr int CP = C + 1;
  __shared__ float nb[KNB][CP];
  __shared__ float sl[KNB];
  __shared__ int nidx[KNB];
  __shared__ float ul[C];
  const float* xTb = xT + (size_t)b * NN * C;
  if (lane < KNB) nidx[lane] = idx[(size_t)(b * NN + n) * KNB + lane];
  for (int c = lane; c < C; c += 64) ul[c] = UT[((size_t)b * NN + n) * C + c];
  __syncthreads();
  for (int i = lane; i < KNB * C; i += 64) {
    int k = i / C, c = i - k * C;
    nb[k][c] = xTb[(size_t)nidx[k] * C + c];
  }
  __syncthreads();
  float sv = -INFINITY;
  if (lane < KNB) {
    float a = 0.f;
#pragma unroll
    for (int c = 0; c < C; ++c) a += nb[lane][c] * ul[c];
    sv = a / sqrtf((float)C);
  }
  float mx = sv;
#pragma unroll
  for (int s = 32; s > 0; s >>= 1) mx = fmaxf(mx, __shfl_xor(mx, s));
  float e = (lane < KNB) ? expf(sv - mx) : 0.f;
  float sum = e;
#pragma unroll
  for (int s = 32; s > 0; s >>= 1) sum += __shfl_xor(sum, s);
  if (lane < KNB) sl[lane] = e / sum;
  __syncthreads();
  const float* xTn = xTb + (size_t)n * C;
  float* op = AGGt + ((size_t)b * NN + n) * C;
  for (int c = lane; c < C; c += 64) {
    float a = 0.f;
#pragma unroll
    for (int k = 0; k < KNB; ++k) a += sl[k] * nb[k][c];
    op[c] = a - xTn[c];
  }
}

// ---------------------------------------------------------------- fused BN (+LReLU)
__global__ __launch_bounds__(256) void bn_fused_kernel(const float* __restrict__ z, int O,
                                                       float* __restrict__ out, int outBS, int c0) {
  int o = blockIdx.x;
  int tid = threadIdx.x;
  __shared__ float s1[256], s2[256];
  __shared__ float smv, srv;
  float a1 = 0.f, a2 = 0.f;
  for (int i = tid; i < BB * NN; i += 256) {
    int b = i >> 11, n = i & (NN - 1);
    float v = z[((size_t)b * O + o) * NN + n];
    a1 += v; a2 += v * v;
  }
  s1[tid] = a1; s2[tid] = a2;
  __syncthreads();
  for (int st = 128; st > 0; st >>= 1) {
    if (tid < st) { s1[tid] += s1[tid + st]; s2[tid] += s2[tid + st]; }
    __syncthreads();
  }
  if (tid == 0) {
    float m = s1[0] / (BB * NN);
    float var = s2[0] / (BB * NN) - m * m;
    smv = m; srv = rsqrtf(var + 1e-5f);
  }
  __syncthreads();
  float m = smv, r = srv;
  for (int i = tid; i < BB * NN; i += 256) {
    int b = i >> 11, n = i & (NN - 1);
    float v = (z[((size_t)b * O + o) * NN + n] - m) * r;
    out[(size_t)b * outBS + (c0 + o) * NN + n] = v >= 0.f ? v : 0.2f * v;
  }
}

// ---------------------------------------------------------------- BN+LReLU into h[:,0:O,:], copy xin into h[:,O:2O,:]
__global__ __launch_bounds__(256) void bn_copy_kernel(const float* __restrict__ z, int O,
                                                      const float* __restrict__ xin, int xbs,
                                                      float* __restrict__ out) {
  int o = blockIdx.x;  // 0..2O-1
  int tid = threadIdx.x;
  int outBS = 2 * O * NN;
  if (o >= O) {
    int c = o - O;
    for (int i = tid; i < BB * NN; i += 256) {
      int b = i >> 11, n = i & (NN - 1);
      out[(size_t)b * outBS + o * NN + n] = xin[(size_t)b * xbs + c * NN + n];
    }
    return;
  }
  __shared__ float s1[256], s2[256];
  __shared__ float smv, srv;
  float a1 = 0.f, a2 = 0.f;
  for (int i = tid; i < BB * NN; i += 256) {
    int b = i >> 11, n = i & (NN - 1);
    float v = z[((size_t)b * O + o) * NN + n];
    a1 += v; a2 += v * v;
  }
  s1[tid] = a1; s2[tid] = a2;
  __syncthreads();
  for (int st = 128; st > 0; st >>= 1) {
    if (tid < st) { s1[tid] += s1[tid + st]; s2[tid] += s2[tid + st]; }
    __syncthreads();
  }
  if (tid == 0) {
    float m = s1[0] / (BB * NN);
    float var = s2[0] / (BB * NN) - m * m;
    smv = m; srv = rsqrtf(var + 1e-5f);
  }
  __syncthreads();
  float m = smv, r = srv;
  for (int i = tid; i < BB * NN; i += 256) {
    int b = i >> 11, n = i & (NN - 1);
    float v = (z[((size_t)b * O + o) * NN + n] - m) * r;
    out[(size_t)b * outBS + o * NN + n] = v >= 0.f ? v : 0.2f * v;
  }
}

// ---------------------------------------------------------------- fused BN+LReLU+max/mean pool (conv5)
__global__ __launch_bounds__(256) void bn_pool_kernel(const float* __restrict__ z,
                                                      float* __restrict__ p) {
  int o = blockIdx.x;
  int tid = threadIdx.x;
  __shared__ float s1[256], s2[256];
  __shared__ float smv, srv;
  float a1 = 0.f, a2 = 0.f;
  for (int i = tid; i < BB * NN; i += 256) {
    int b = i >> 11, n = i & (NN - 1);
    float v = z[((size_t)b * 1024 + o) * NN + n];
    a1 += v; a2 += v * v;
  }
  s1[tid] = a1; s2[tid] = a2;
  __syncthreads();
  for (int st = 128; st > 0; st >>= 1) {
    if (tid < st) { s1[tid] += s1[tid + st]; s2[tid] += s2[tid + st]; }
    __syncthreads();
  }
  if (tid == 0) {
    float m = s1[0] / (BB * NN);
    float var = s2[0] / (BB * NN) - m * m;
    smv = m; srv = rsqrtf(var + 1e-5f);
  }
  __syncthreads();
  float m = smv, r = srv;
  int b = tid >> 5, l = tid & 31;
  const float* zp = z + ((size_t)b * 1024 + o) * NN;
  float mx = -INFINITY, sm = 0.f;
  for (int n = l; n < NN; n += 32) {
    float v = (zp[n] - m) * r;
    v = v >= 0.f ? v : 0.2f * v;
    mx = fmaxf(mx, v); sm += v;
  }
#pragma unroll
  for (int s = 16; s > 0; s >>= 1) {
    mx = fmaxf(mx, __shfl_xor(mx, s));
    sm += __shfl_xor(sm, s);
  }
  if (l == 0) {
    p[b * 2048 + o] = mx;
    p[b * 2048 + 1024 + o] = sm * (1.f / NN);
  }
}

__global__ __launch_bounds__(64) void linear_kernel(const float* __restrict__ in, int IN, int OUT,
                                                    const float* __restrict__ w,
                                                    const float* __restrict__ bias,
                                                    float* __restrict__ out) {
  int o = blockIdx.x;
  int b = o / OUT, f = o % OUT;
  const float* ip = in + (size_t)b * IN;
  const float* wp = w + (size_t)f * IN;
  float a = 0.f;
  for (int i = threadIdx.x; i < IN; i += 64) a += ip[i] * wp[i];
#pragma unroll
  for (int s = 32; s > 0; s >>= 1) a += __shfl_down(a, s);
  if (threadIdx.x == 0) out[o] = a + bias[f];
}

__global__ __launch_bounds__(256) void bnf_kernel(float* __restrict__ t, int F) {
  int f = blockIdx.x * blockDim.x + threadIdx.x;
  if (f >= F) return;
  float s = 0.f, s2 = 0.f;
  for (int b = 0; b < BB; ++b) { float v = t[b * F + f]; s += v; s2 += v * v; }
  float m = s * (1.f / BB);
  float var = s2 * (1.f / BB) - m * m;
  float r = rsqrtf(var + 1e-5f);
  for (int b = 0; b < BB; ++b) {
    float v = (t[b * F + f] - m) * r;
    t[b * F + f] = v >= 0.f ? v : 0.2f * v;
  }
}

// ---------------------------------------------------------------- host side

struct SAW { const float *wq, *wk, *wv, *wc; };

static inline void run_conv(const float* in, int inBS, int C, int O, const float* w,
                            float* z, hipStream_t st) {
  if (O % 128 == 0)
    conv_gemm128_db_kernel<<<dim3(NN / 128, O / 128, BB), 256, 0, st>>>(in, inBS, C, O, w, z);
  else
    conv_gemm_kernel<<<dim3(NN / 64, (O + 63) / 64, BB), 256, 0, st>>>(in, inBS, C, O, w, z);
}

// MFMA==true only valid for C multiple of 64 (uses mfma_gemm).
template <int C, bool MFMA>
static inline void run_sa(const float* xin, int xbs, SAW w,
                          float* xT, float* U, float* UT, float* AGGt,
                          float* AGG, float* z, float* h, float* sq, int* idx,
                          float* M, float* WCV, unsigned short* Mb, unsigned short* wcvb,
                          unsigned short* xTb, unsigned short* AGGtb,
                          float* D, int nbatch, hipStream_t st) {
  sq_kernel<<<BB * NN / 256, 256, 0, st>>>(xin, xbs, C, sq);
  transpose_kernel<<<dim3(NN / 32, (C + 31) / 32, BB), 256, 0, st>>>(xin, xbs, C, NN, xT);
  mprep_kernel<<<(C * C + 255) / 256, 256, 0, st>>>(w.wq, w.wk, C, M);
  wcv_kernel<<<(C * C + 255) / 256, 256, 0, st>>>(w.wc, w.wv, C, WCV);
  if (MFMA) {
    convert_bf16_kernel<<<(C * C + 255) / 256, 256, 0, st>>>(M, Mb, C * C);
    convert_bf16_kernel<<<(C * C + 255) / 256, 256, 0, st>>>(WCV, wcvb, C * C);
    transpose_bf16_kernel<<<dim3(NN / 32, (C + 31) / 32, BB), 256, 0, st>>>(xin, xbs, C, NN, xTb);
  }
  for (int bb = 0; bb < BB; bb += nbatch) {
    int nbc = (BB - bb) < nbatch ? (BB - bb) : nbatch;
    pd_gemm128_db_kernel<<<dim3(NN / 128, NN / 128, nbc), 256, 0, st>>>(xin, xbs, C, sq, D, bb);
    topk_kernel<<<dim3(NN, nbc), 64, 0, st>>>(D, idx, bb);
  }
  if (MFMA)
    mfma_gemm_kernel<<<dim3(NN / 128, C / 64, BB), 256, 0, st>>>(Mb, xTb, U, C, C);
  else
    run_conv(xin, xbs, C, C, M, U, st);                            // U = M . x  [C][N]
  transpose_kernel<<<dim3(NN / 32, (C + 31) / 32, BB), 256, 0, st>>>(U, C * NN, C, NN, UT);
  att_wave_kernel<C><<<BB * NN, 64, 0, st>>>(xT, UT, idx, AGGt);   // AGGt [N][C]
  if (MFMA) {
    convert_bf16_kernel<<<(BB * NN * C + 255) / 256, 256, 0, st>>>(AGGt, AGGtb, BB * NN * C);
    mfma_gemm_kernel<<<dim3(NN / 128, C / 64, BB), 256, 0, st>>>(wcvb, AGGtb, z, C, C);
  } else {
    transpose_kernel<<<dim3((C + 31) / 32, NN / 32, BB), 256, 0, st>>>(AGGt, NN * C, NN, C, AGG);
    run_conv(AGG, C * NN, C, C, WCV, z, st);                       // Z = (wc.wv) . AGG
  }
  bn_copy_kernel<<<2 * C, 256, 0, st>>>(z, C, xin, xbs, h);
}

static inline void run_conv_bn(const float* in, int inBS, int Cin, int O, const float* w,
                               float* z, float* out, int outBS, int c0, hipStream_t st) {
  run_conv(in, inBS, Cin, O, w, z, st);
  bn_fused_kernel<<<O, 256, 0, st>>>(z, O, out, outBS, c0);
}

extern "C" void kernel_launch(void* const* d_in, const int* in_sizes, int n_in,
                              void* d_out, int out_size, void* d_ws, size_t ws_size,
                              hipStream_t stream) {
  const float* x = (const float*)d_in[0];
  SAW sa1{(const float*)d_in[1], (const float*)d_in[2], (const float*)d_in[3], (const float*)d_in[4]};
  SAW sa2{(const float*)d_in[5], (const float*)d_in[6], (const float*)d_in[7], (const float*)d_in[8]};
  SAW sa3{(const float*)d_in[9], (const float*)d_in[10], (const float*)d_in[11], (const float*)d_in[12]};
  SAW sa4{(const float*)d_in[13], (const float*)d_in[14], (const float*)d_in[15], (const float*)d_in[16]};
  const float* conv1_w = (const float*)d_in[17];
  const float* conv2_w = (const float*)d_in[18];
  const float* conv3_w = (const float*)d_in[19];
  const float* conv4_w = (const float*)d_in[20];
  const float* conv5_w = (const float*)d_in[21];
  const float* lin1_w = (const float*)d_in[22];
  const float* lin1_b = (const float*)d_in[23];
  const float* lin2_w = (const float*)d_in[24];
  const float* lin2_b = (const float*)d_in[25];
  const float* lin3_w = (const float*)d_in[26];
  const float* lin3_b = (const float*)d_in[27];

  char* ws = (char*)d_ws;
  size_t off = 0;
  auto take = [&](size_t bytes) -> void* {
    void* p = ws + off;
    off += (bytes + 255) & ~(size_t)255;
    return p;
  };
  float* sq   = (float*)take((size_t)BB * NN * 4);
  int*   idx  = (int*)take((size_t)BB * NN * KNB * 4);
  float* M    = (float*)take((size_t)128 * 128 * 4);
  float* WCV  = (float*)take((size_t)128 * 128 * 4);
  unsigned short* Mb   = (unsigned short*)take((size_t)128 * 128 * 2);
  unsigned short* wcvb = (unsigned short*)take((size_t)128 * 128 * 2);
  unsigned short* w4b  = (unsigned short*)take((size_t)256 * 256 * 2);
  unsigned short* w5b  = (unsigned short*)take((size_t)1024 * 512 * 2);
  float* U    = (float*)take((size_t)BB * 128 * NN * 4);  // contiguous with AGG
  float* AGG  = (float*)take((size_t)BB * 128 * NN * 4);  // also hosts xT
  float* h    = (float*)take((size_t)BB * 256 * NN * 4);  // first half hosts UT
  float* z    = (float*)take((size_t)BB * 1024 * NN * 4); // hosts AGGt, AGGtb(+16MB), D-chunks
  float* xc   = (float*)take((size_t)BB * 512 * NN * 4);
  float* p    = (float*)take((size_t)BB * 2048 * 4);
  float* t1   = (float*)take((size_t)BB * 512 * 4);
  float* t2   = (float*)take((size_t)BB * 256 * 4);
  (void)n_in; (void)in_sizes; (void)out_size;

  // Overlays (phase-ordered lifetimes):
  float* xT = AGG;                                          // dead before AGG written
  float* UT = h;                                            // consumed before h written
  float* AGGt = z;                                          // first 8.4 MB of z
  unsigned short* xTb   = (unsigned short*)((char*)h + (size_t)BB * 128 * NN * 4);  // h 2nd half
  unsigned short* AGGtb = (unsigned short*)((char*)z + (size_t)16 * 1024 * 1024);   // z + 16 MB
  unsigned short* hTb   = (unsigned short*)U;               // conv4 phase (U dead)
  unsigned short* xcTb  = (unsigned short*)U;               // conv5 phase (U+AGG dead, 16.8 MB)

  size_t dfull = (size_t)BB * NN * NN * 4;
  bool fullD = (ws_size > off + dfull + 4096);
  float* D = fullD ? (float*)take(dfull) : z;               // !fullD: 3-batch chunks in z
  int nbatch = fullD ? BB : 3;

  // SA1 (C=3) -> h [B,6,N]
  run_sa<3, false>(x, 3 * NN, sa1, xT, U, UT, AGGt, AGG, z, h, sq, idx,
                   M, WCV, Mb, wcvb, xTb, AGGtb, D, nbatch, stream);
  run_conv_bn(h, 6 * NN, 6, 64, conv1_w, z, xc, 512 * NN, 0, stream);
  // SA2 (C=64) on x1
  run_sa<64, false>(xc + 0 * NN, 512 * NN, sa2, xT, U, UT, AGGt, AGG, z, h, sq, idx,
                    M, WCV, Mb, wcvb, xTb, AGGtb, D, nbatch, stream);
  run_conv_bn(h, 128 * NN, 128, 64, conv2_w, z, xc, 512 * NN, 64, stream);
  // SA3 (C=64) on x2
  run_sa<64, false>(xc + 64 * NN, 512 * NN, sa3, xT, U, UT, AGGt, AGG, z, h, sq, idx,
                    M, WCV, Mb, wcvb, xTb, AGGtb, D, nbatch, stream);
  run_conv_bn(h, 128 * NN, 128, 128, conv3_w, z, xc, 512 * NN, 128, stream);
  // SA4 (C=128) on x3 — bf16 MFMA for U and Z convs (no kNN downstream)
  run_sa<128, true>(xc + 128 * NN, 512 * NN, sa4, xT, U, UT, AGGt, AGG, z, h, sq, idx,
                    M, WCV, Mb, wcvb, xTb, AGGtb, D, nbatch, stream);
  // conv4 (bf16 MFMA): h [B,256,N] -> z [B,256,N]
  transpose_bf16_kernel<<<dim3(NN / 32, 8, BB), 256, 0, stream>>>(h, 256 * NN, 256, NN, hTb);
  convert_bf16_kernel<<<(256 * 256 + 255) / 256, 256, 0, stream>>>(conv4_w, w4b, 256 * 256);
  mfma_gemm_kernel<<<dim3(NN / 128, 4, BB), 256, 0, stream>>>(w4b, hTb, z, 256, 256);
  bn_fused_kernel<<<256, 256, 0, stream>>>(z, 256, xc, 512 * NN, 256);
  // conv5 (bf16 MFMA): xc [B,512,N] -> z [B,1024,N]; BN+LReLU+pool -> p
  transpose_bf16_kernel<<<dim3(NN / 32, 16, BB), 256, 0, stream>>>(xc, 512 * NN, 512, NN, xcTb);
  convert_bf16_kernel<<<(1024 * 512 + 255) / 256, 256, 0, stream>>>(conv5_w, w5b, 1024 * 512);
  mfma_gemm_kernel<<<dim3(NN / 128, 16, BB), 256, 0, stream>>>(w5b, xcTb, z, 1024, 512);
  bn_pool_kernel<<<1024, 256, 0, stream>>>(z, p);
  // FC head
  linear_kernel<<<BB * 512, 64, 0, stream>>>(p, 2048, 512, lin1_w, lin1_b, t1);
  bnf_kernel<<<2, 256, 0, stream>>>(t1, 512);
  linear_kernel<<<BB * 256, 64, 0, stream>>>(t1, 512, 256, lin2_w, lin2_b, t2);
  bnf_kernel<<<1, 256, 0, stream>>>(t2, 256);
  linear_kernel<<<BB * 40, 64, 0, stream>>>(t2, 256, 40, lin3_w, lin3_b, (float*)d_out);
}

// Round 9
// 1766.506 us; speedup vs baseline: 1.8650x; 1.0406x over previous
//
#include <hip/hip_runtime.h>
#include <math.h>

#define BB 8
#define NN 2048
#define KNB 20

typedef __attribute__((ext_vector_type(8))) short bf16x8;
typedef __attribute__((ext_vector_type(4))) float f32x4;

__device__ inline unsigned short f2bf(float f) {
  union { float f; unsigned u; } v; v.f = f;
  unsigned r = v.u + 0x7FFF + ((v.u >> 16) & 1);  // RNE
  return (unsigned short)(r >> 16);
}

// ---------------------------------------------------------------- sq
__global__ __launch_bounds__(256) void sq_kernel(const float* __restrict__ x, int bs, int C,
                                                 float* __restrict__ sq) {
  int t = blockIdx.x * blockDim.x + threadIdx.x;
  int b = t / NN, n = t % NN;
  const float* xp = x + (size_t)b * bs + n;
  float s = 0.f;
  for (int c = 0; c < C; ++c) { float v = xp[c * NN]; s += v * v; }
  sq[t] = s;
}

// ---------------------------------------------------------------- M = wk^T wq
__global__ __launch_bounds__(256) void mprep_kernel(const float* __restrict__ wq,
                                                    const float* __restrict__ wk, int C,
                                                    float* __restrict__ M) {
  int T = blockIdx.x * 256 + threadIdx.x;
  if (T >= C * C) return;
  int c = T / C, cp = T % C;
  float a = 0.f;
  for (int e = 0; e < C; ++e) a += wk[e * C + c] * wq[e * C + cp];
  M[c * C + cp] = a;
}

// ---------------------------------------------------------------- wcv = wc @ wv
__global__ __launch_bounds__(256) void wcv_kernel(const float* __restrict__ wc,
                                                  const float* __restrict__ wv, int C,
                                                  float* __restrict__ out) {
  int T = blockIdx.x * 256 + threadIdx.x;
  if (T >= C * C) return;
  int o = T / C, c = T % C;
  float a = 0.f;
  for (int e = 0; e < C; ++e) a += wc[o * C + e] * wv[e * C + c];
  out[o * C + c] = a;
}

// ---------------------------------------------------------------- converts
__global__ __launch_bounds__(256) void convert_bf16_kernel(const float* __restrict__ in,
                                                           unsigned short* __restrict__ out,
                                                           int count) {
  int i = blockIdx.x * 256 + threadIdx.x;
  if (i < count) out[i] = f2bf(in[i]);
}

// ---------------------------------------------------------------- transpose (fp32)
__global__ __launch_bounds__(256) void transpose_kernel(const float* __restrict__ in, int inBS,
                                                        int R, int Cl, float* __restrict__ out) {
  __shared__ float tile[32][33];
  int b = blockIdx.z;
  const float* ip = in + (size_t)b * inBS;
  float* op = out + (size_t)b * R * Cl;
  int c0 = blockIdx.x * 32, r0 = blockIdx.y * 32;
  int tx = threadIdx.x & 31, ty = threadIdx.x >> 5;
  for (int yy = ty; yy < 32; yy += 8) {
    int r = r0 + yy, c = c0 + tx;
    tile[yy][tx] = (r < R && c < Cl) ? ip[(size_t)r * Cl + c] : 0.f;
  }
  __syncthreads();
  for (int yy = ty; yy < 32; yy += 8) {
    int c = c0 + yy, r = r0 + tx;
    if (c < Cl && r < R) op[(size_t)c * R + r] = tile[tx][yy];
  }
}

// ---------------------------------------------------------------- transpose + bf16 convert
__global__ __launch_bounds__(256) void transpose_bf16_kernel(const float* __restrict__ in, int inBS,
                                                             int R, int Cl,
                                                             unsigned short* __restrict__ out) {
  __shared__ float tile[32][33];
  int b = blockIdx.z;
  const float* ip = in + (size_t)b * inBS;
  unsigned short* op = out + (size_t)b * R * Cl;
  int c0 = blockIdx.x * 32, r0 = blockIdx.y * 32;
  int tx = threadIdx.x & 31, ty = threadIdx.x >> 5;
  for (int yy = ty; yy < 32; yy += 8) {
    int r = r0 + yy, c = c0 + tx;
    tile[yy][tx] = (r < R && c < Cl) ? ip[(size_t)r * Cl + c] : 0.f;
  }
  __syncthreads();
  for (int yy = ty; yy < 32; yy += 8) {
    int c = c0 + yy, r = r0 + tx;
    if (c < Cl && r < R) op[(size_t)c * R + r] = f2bf(tile[tx][yy]);
  }
}

// ---------------------------------------------------------------- MFMA GEMM, LDS double-buffered
// Z[b][o][n] = sum_k A[o][k] * B[b][n][k]; A,B bf16 K-contiguous, Z fp32.
// Block 256 thr = 4 waves (2x2), tile 128o x 128n, K-chunk 32; one barrier
// per chunk, prefetch staged in registers (r7-proven skeleton). LDS tiles in
// FRAGMENT ORDER: 16B piece index X = subtile*64 + q*16 + l16, so frag loads
// and staging stores are lane-contiguous ds_*_b128 (canonical pattern).
// O%128==0, K%32==0, N%128==0.
__global__ __launch_bounds__(256, 2) void mfma_gemm_lds_kernel(
    const unsigned short* __restrict__ A, const unsigned short* __restrict__ B,
    float* __restrict__ Z, int O, int K) {
  const int b = blockIdx.z;
  const int n0 = blockIdx.x * 128, o0 = blockIdx.y * 128;
  const int tid = threadIdx.x;
  const int wave = tid >> 6, lane = tid & 63;
  const int wo = wave >> 1, wn = wave & 1;   // 64x64 quadrant per wave
  const int l16 = lane & 15, q = lane >> 4;
  __shared__ unsigned short Al[2][4096];     // 128 rows x 32 k (8 KB), frag order
  __shared__ unsigned short Bl[2][4096];
  const unsigned short* Ab = A + (size_t)o0 * K;
  const unsigned short* Bb = B + ((size_t)b * NN + n0) * K;

  // staging pieces: p in [0,512): s=p>>6, qq=(p>>4)&3, l=p&15 -> row s*16+l, col qq*8
  const int p0 = tid, p1 = tid + 256;
  const int r0 = ((p0 >> 6) << 4) | (p0 & 15), c0 = ((p0 >> 4) & 3) * 8;
  const int r1 = ((p1 >> 6) << 4) | (p1 & 15), c1 = ((p1 >> 4) & 3) * 8;

  bf16x8 ar0, ar1, br0, br1;
  auto gload = [&](int k0) {
    ar0 = *(const bf16x8*)(Ab + (size_t)r0 * K + k0 + c0);
    ar1 = *(const bf16x8*)(Ab + (size_t)r1 * K + k0 + c1);
    br0 = *(const bf16x8*)(Bb + (size_t)r0 * K + k0 + c0);
    br1 = *(const bf16x8*)(Bb + (size_t)r1 * K + k0 + c1);
  };
  auto sstore = [&](int buf) {
    *(bf16x8*)&Al[buf][p0 * 8] = ar0;
    *(bf16x8*)&Al[buf][p1 * 8] = ar1;
    *(bf16x8*)&Bl[buf][p0 * 8] = br0;
    *(bf16x8*)&Bl[buf][p1 * 8] = br1;
  };

  f32x4 acc[4][4];
#pragma unroll
  for (int s = 0; s < 4; ++s)
#pragma unroll
    for (int t = 0; t < 4; ++t) acc[s][t] = (f32x4){0.f, 0.f, 0.f, 0.f};

  gload(0);
  sstore(0);
  int cur = 0;
  for (int k0 = 0; k0 < K; k0 += 32) {
    bool more = (k0 + 32) < K;
    if (more) gload(k0 + 32);
    __syncthreads();
    bf16x8 af[4], bfr[4];
#pragma unroll
    for (int s = 0; s < 4; ++s)
      af[s] = *(const bf16x8*)&Al[cur][((wo * 4 + s) * 64 + q * 16 + l16) * 8];
#pragma unroll
    for (int t = 0; t < 4; ++t)
      bfr[t] = *(const bf16x8*)&Bl[cur][((wn * 4 + t) * 64 + q * 16 + l16) * 8];
#pragma unroll
    for (int s = 0; s < 4; ++s)
#pragma unroll
      for (int t = 0; t < 4; ++t)
        acc[s][t] = __builtin_amdgcn_mfma_f32_16x16x32_bf16(af[s], bfr[t], acc[s][t], 0, 0, 0);
    if (more) sstore(cur ^ 1);
    cur ^= 1;
  }
#pragma unroll
  for (int s = 0; s < 4; ++s)
#pragma unroll
    for (int t = 0; t < 4; ++t) {
      float* zp = Z + ((size_t)b * O + o0 + wo * 64 + s * 16 + q * 4) * NN
                  + n0 + wn * 64 + t * 16 + l16;
#pragma unroll
      for (int r = 0; r < 4; ++r) zp[(size_t)r * NN] = acc[s][t][r];
    }
}

// ---------------------------------------------------------------- pd GEMM 128-tile, double-buffered
// __launch_bounds__(256,2): (256,3) capped VGPR at 84 and spilled (r6).
__global__ __launch_bounds__(256, 2) void pd_gemm128_db_kernel(
    const float* __restrict__ x, int bs, int C, const float* __restrict__ sq,
    float* __restrict__ P, int b_base) {
  const int b = b_base + blockIdx.z;
  const int n0 = blockIdx.x * 128, m0 = blockIdx.y * 128;
  const int tid = threadIdx.x;
  const int tm = tid & 15, tn = tid >> 4;
  __shared__ float As[2][16][128], Bs[2][16][128];
  const float* xb = x + (size_t)b * bs;
  float acc[8][8];
#pragma unroll
  for (int i = 0; i < 8; ++i)
#pragma unroll
    for (int j = 0; j < 8; ++j) acc[i][j] = 0.f;

  float4 ara[2], arb[2];
  auto load_tile = [&](int k0) {
#pragma unroll
    for (int it = 0; it < 2; ++it) {
      int i = it * 256 + tid;
      int kc = i >> 5, c4 = i & 31;
      bool ok = (k0 + kc) < C;
      ara[it] = ok ? *(const float4*)&xb[(size_t)(k0 + kc) * NN + n0 + c4 * 4]
                   : make_float4(0.f, 0.f, 0.f, 0.f);
      arb[it] = ok ? *(const float4*)&xb[(size_t)(k0 + kc) * NN + m0 + c4 * 4]
                   : make_float4(0.f, 0.f, 0.f, 0.f);
    }
  };
  auto store_tile = [&](int buf) {
#pragma unroll
    for (int it = 0; it < 2; ++it) {
      int i = it * 256 + tid;
      int kc = i >> 5, c4 = i & 31;
      *(float4*)&As[buf][kc][c4 * 4] = ara[it];
      *(float4*)&Bs[buf][kc][c4 * 4] = arb[it];
    }
  };

  load_tile(0);
  store_tile(0);
  int cur = 0;
  for (int k0 = 0; k0 < C; k0 += 16) {
    bool more = (k0 + 16) < C;
    if (more) load_tile(k0 + 16);
    __syncthreads();
#pragma unroll
    for (int kc = 0; kc < 16; ++kc) {
      float4 a0 = *(const float4*)&As[cur][kc][tn * 4];
      float4 a1 = *(const float4*)&As[cur][kc][64 + tn * 4];
      float4 b0 = *(const float4*)&Bs[cur][kc][tm * 4];
      float4 b1 = *(const float4*)&Bs[cur][kc][64 + tm * 4];
      float ar[8] = {a0.x, a0.y, a0.z, a0.w, a1.x, a1.y, a1.z, a1.w};
      float br[8] = {b0.x, b0.y, b0.z, b0.w, b1.x, b1.y, b1.z, b1.w};
#pragma unroll
      for (int i = 0; i < 8; ++i)
#pragma unroll
        for (int j = 0; j < 8; ++j) acc[i][j] += ar[i] * br[j];
    }
    if (more) store_tile(cur ^ 1);
    cur ^= 1;
  }
  float4 sqa = *(const float4*)&sq[b * NN + m0 + tm * 4];
  float4 sqb = *(const float4*)&sq[b * NN + m0 + 64 + tm * 4];
#pragma unroll
  for (int h = 0; h < 2; ++h)
#pragma unroll
    for (int i = 0; i < 4; ++i) {
      int r = h * 4 + i;
      int nn = n0 + h * 64 + tn * 4 + i;
      float* prow = &P[((size_t)blockIdx.z * NN + nn) * NN + m0];
      float4 o0, o1;
      o0.x = 2.f * acc[r][0] - sqa.x; o0.y = 2.f * acc[r][1] - sqa.y;
      o0.z = 2.f * acc[r][2] - sqa.z; o0.w = 2.f * acc[r][3] - sqa.w;
      o1.x = 2.f * acc[r][4] - sqb.x; o1.y = 2.f * acc[r][5] - sqb.y;
      o1.z = 2.f * acc[r][6] - sqb.z; o1.w = 2.f * acc[r][7] - sqb.w;
      *(float4*)&prow[tm * 4] = o0;
      *(float4*)&prow[64 + tm * 4] = o1;
    }
}

// ---------------------------------------------------------------- one-wave top-20
__global__ __launch_bounds__(64) void topk_kernel(const float* __restrict__ P,
                                                  int* __restrict__ idx, int b_base) {
  const int n = blockIdx.x;
  const int bl = blockIdx.y;
  const int b = b_base + bl;
  const int lane = threadIdx.x;
  const float* row = P + ((size_t)bl * NN + n) * NN;
  const float4* rp = (const float4*)row;
  float v[32];
#pragma unroll
  for (int qq = 0; qq < 8; ++qq) {
    float4 vv = rp[qq * 64 + lane];
    int mb = qq * 256 + lane * 4;
    v[qq * 4 + 0] = (mb + 0 == n) ? -INFINITY : vv.x;
    v[qq * 4 + 1] = (mb + 1 == n) ? -INFINITY : vv.y;
    v[qq * 4 + 2] = (mb + 2 == n) ? -INFINITY : vv.z;
    v[qq * 4 + 3] = (mb + 3 == n) ? -INFINITY : vv.w;
  }
  int* op = idx + (size_t)(b * NN + n) * KNB;
  for (int k = 0; k < KNB; ++k) {
    float bv = v[0]; int bj = 0;
#pragma unroll
    for (int j = 1; j < 32; ++j)
      if (v[j] > bv) { bv = v[j]; bj = j; }
    int bm = (bj >> 2) * 256 + lane * 4 + (bj & 3);
#pragma unroll
    for (int s = 32; s > 0; s >>= 1) {
      float ov = __shfl_down(bv, s);
      int om = __shfl_down(bm, s);
      if (ov > bv) { bv = ov; bm = om; }
    }
    bm = __shfl(bm, 0);
    if (lane == 0) op[k] = bm;
    if (((bm >> 2) & 63) == lane) {
      int jj = ((bm >> 8) << 2) | (bm & 3);
#pragma unroll
      for (int j = 0; j < 32; ++j)
        if (j == jj) v[j] = -INFINITY;
    }
  }
}

// ---------------------------------------------------------------- conv GEMM 64-tile (small O)
__global__ __launch_bounds__(256, 2) void conv_gemm_kernel(
    const float* __restrict__ in, int inBS, int C, int O,
    const float* __restrict__ w, float* __restrict__ z) {
  const int b = blockIdx.z;
  const int n0 = blockIdx.x * 64, o0 = blockIdx.y * 64;
  const int tid = threadIdx.x;
  const int tm = tid & 15, tn = tid >> 4;
  __shared__ float Ws[16][68];
  __shared__ float Xs[16][64];
  const float* ib = in + (size_t)b * inBS;
  float acc[4][4];
#pragma unroll
  for (int i = 0; i < 4; ++i)
#pragma unroll
    for (int j = 0; j < 4; ++j) acc[i][j] = 0.f;

  for (int k0 = 0; k0 < C; k0 += 16) {
    __syncthreads();
#pragma unroll
    for (int it = 0; it < 4; ++it) {
      int i = it * 256 + tid;
      int kc = i >> 6, nl = i & 63;
      Xs[kc][nl] = ((k0 + kc) < C) ? ib[(size_t)(k0 + kc) * NN + n0 + nl] : 0.f;
      int ol = i >> 4, kc2 = i & 15;
      Ws[kc2][ol] = ((o0 + ol) < O && (k0 + kc2) < C) ? w[(size_t)(o0 + ol) * C + k0 + kc2] : 0.f;
    }
    __syncthreads();
#pragma unroll
    for (int kc = 0; kc < 16; ++kc) {
      float4 a = *(const float4*)&Ws[kc][tn * 4];
      float4 bv = *(const float4*)&Xs[kc][tm * 4];
      acc[0][0] += a.x * bv.x; acc[0][1] += a.x * bv.y; acc[0][2] += a.x * bv.z; acc[0][3] += a.x * bv.w;
      acc[1][0] += a.y * bv.x; acc[1][1] += a.y * bv.y; acc[1][2] += a.y * bv.z; acc[1][3] += a.y * bv.w;
      acc[2][0] += a.z * bv.x; acc[2][1] += a.z * bv.y; acc[2][2] += a.z * bv.z; acc[2][3] += a.z * bv.w;
      acc[3][0] += a.w * bv.x; acc[3][1] += a.w * bv.y; acc[3][2] += a.w * bv.z; acc[3][3] += a.w * bv.w;
    }
  }
#pragma unroll
  for (int i = 0; i < 4; ++i) {
    int o = o0 + tn * 4 + i;
    if (o < O) {
      float4 ov;
      ov.x = acc[i][0]; ov.y = acc[i][1]; ov.z = acc[i][2]; ov.w = acc[i][3];
      *(float4*)&z[((size_t)b * O + o) * NN + n0 + tm * 4] = ov;
    }
  }
}

// ---------------------------------------------------------------- conv GEMM 128-tile, double-buffered
__global__ __launch_bounds__(256, 2) void conv_gemm128_db_kernel(
    const float* __restrict__ in, int inBS, int C, int O,
    const float* __restrict__ w, float* __restrict__ z) {
  const int b = blockIdx.z;
  const int n0 = blockIdx.x * 128, o0 = blockIdx.y * 128;
  const int tid = threadIdx.x;
  const int tm = tid & 15, tn = tid >> 4;
  __shared__ float Xs[2][16][128];
  __shared__ float Ws[2][16][132];
  const float* ib = in + (size_t)b * inBS;
  float acc[8][8];
#pragma unroll
  for (int i = 0; i < 8; ++i)
#pragma unroll
    for (int j = 0; j < 8; ++j) acc[i][j] = 0.f;

  float4 xr[2], wr[2];
  auto load_tile = [&](int k0) {
#pragma unroll
    for (int it = 0; it < 2; ++it) {
      int i = it * 256 + tid;
      int kc = i >> 5, c4 = i & 31;
      xr[it] = ((k0 + kc) < C) ? *(const float4*)&ib[(size_t)(k0 + kc) * NN + n0 + c4 * 4]
                               : make_float4(0.f, 0.f, 0.f, 0.f);
      int ol = i >> 2, kq = i & 3;
      wr[it] = ((k0 + kq * 4) < C) ? *(const float4*)&w[(size_t)(o0 + ol) * C + k0 + kq * 4]
                                   : make_float4(0.f, 0.f, 0.f, 0.f);
    }
  };
  auto store_tile = [&](int buf) {
#pragma unroll
    for (int it = 0; it < 2; ++it) {
      int i = it * 256 + tid;
      int kc = i >> 5, c4 = i & 31;
      *(float4*)&Xs[buf][kc][c4 * 4] = xr[it];
      int ol = i >> 2, kq = i & 3;
      Ws[buf][kq * 4 + 0][ol] = wr[it].x;
      Ws[buf][kq * 4 + 1][ol] = wr[it].y;
      Ws[buf][kq * 4 + 2][ol] = wr[it].z;
      Ws[buf][kq * 4 + 3][ol] = wr[it].w;
    }
  };

  load_tile(0);
  store_tile(0);
  int cur = 0;
  for (int k0 = 0; k0 < C; k0 += 16) {
    bool more = (k0 + 16) < C;
    if (more) load_tile(k0 + 16);
    __syncthreads();
#pragma unroll
    for (int kc = 0; kc < 16; ++kc) {
      float4 a0 = *(const float4*)&Ws[cur][kc][tn * 4];
      float4 a1 = *(const float4*)&Ws[cur][kc][64 + tn * 4];
      float4 b0 = *(const float4*)&Xs[cur][kc][tm * 4];
      float4 b1 = *(const float4*)&Xs[cur][kc][64 + tm * 4];
      float ar[8] = {a0.x, a0.y, a0.z, a0.w, a1.x, a1.y, a1.z, a1.w};
      float br[8] = {b0.x, b0.y, b0.z, b0.w, b1.x, b1.y, b1.z, b1.w};
#pragma unroll
      for (int i = 0; i < 8; ++i)
#pragma unroll
        for (int j = 0; j < 8; ++j) acc[i][j] += ar[i] * br[j];
    }
    if (more) store_tile(cur ^ 1);
    cur ^= 1;
  }
#pragma unroll
  for (int h = 0; h < 2; ++h)
#pragma unroll
    for (int i = 0; i < 4; ++i) {
      int r = h * 4 + i;
      int o = o0 + h * 64 + tn * 4 + i;
      float* zrow = &z[((size_t)b * O + o) * NN + n0];
      float4 o0v, o1v;
      o0v.x = acc[r][0]; o0v.y = acc[r][1]; o0v.z = acc[r][2]; o0v.w = acc[r][3];
      o1v.x = acc[r][4]; o1v.y = acc[r][5]; o1v.z = acc[r][6]; o1v.w = acc[r][7];
      *(float4*)&zrow[tm * 4] = o0v;
      *(float4*)&zrow[64 + tm * 4] = o1v;
    }
}

// ---------------------------------------------------------------- attention (wave/point)
template <int C>
__global__ __launch_bounds__(64) void att_wave_kernel(
    const float* __restrict__ xT, const float* __restrict__ UT,
    const int* __restrict__ idx, float* __restrict__ AGGt) {
  const int n = blockIdx.x & (NN - 1);
  const int b = blockIdx.x >> 11;
  const int lane = threadIdx.x;
  constexpr int CP = C + 1;
  __shared__ float nb[KNB][CP];
  __shared__ float sl[KNB];
  __shared__ int nidx[KNB];
  __shared__ float ul[C];
  const float* xTb = xT + (size_t)b * NN * C;
  if (lane < KNB) nidx[lane] = idx[(size_t)(b * NN + n) * KNB + lane];
  for (int c = lane; c < C; c += 64) ul[c] = UT[((size_t)b * NN + n) * C + c];
  __syncthreads();
  for (int i = lane; i < KNB * C; i += 64) {
    int k = i / C, c = i - k * C;
    nb[k][c] = xTb[(size_t)nidx[k] * C + c];
  }
  __syncthreads();
  float sv = -INFINITY;
  if (lane < KNB) {
    float a = 0.f;
#pragma unroll
    for (int c = 0; c < C; ++c) a += nb[lane][c] * ul[c];
    sv = a / sqrtf((float)C);
  }
  float mx = sv;
#pragma unroll
  for (int s = 32; s > 0; s >>= 1) mx = fmaxf(mx, __shfl_xor(mx, s));
  float e = (lane < KNB) ? expf(sv - mx) : 0.f;
  float sum = e;
#pragma unroll
  for (int s = 32; s > 0; s >>= 1) sum += __shfl_xor(sum, s);
  if (lane < KNB) sl[lane] = e / sum;
  __syncthreads();
  const float* xTn = xTb + (size_t)n * C;
  float* op = AGGt + ((size_t)b * NN + n) * C;
  for (int c = lane; c < C; c += 64) {
    float a = 0.f;
#pragma unroll
    for (int k = 0; k < KNB; ++k) a += sl[k] * nb[k][c];
    op[c] = a - xTn[c];
  }
}

// ---------------------------------------------------------------- fused BN (+LReLU)
__global__ __launch_bounds__(256) void bn_fused_kernel(const float* __restrict__ z, int O,
                                                       float* __restrict__ out, int outBS, int c0) {
  int o = blockIdx.x;
  int tid = threadIdx.x;
  __shared__ float s1[256], s2[256];
  __shared__ float smv, srv;
  float a1 = 0.f, a2 = 0.f;
  for (int i = tid; i < BB * NN; i += 256) {
    int b = i >> 11, n = i & (NN - 1);
    float v = z[((size_t)b * O + o) * NN + n];
    a1 += v; a2 += v * v;
  }
  s1[tid] = a1; s2[tid] = a2;
  __syncthreads();
  for (int st = 128; st > 0; st >>= 1) {
    if (tid < st) { s1[tid] += s1[tid + st]; s2[tid] += s2[tid + st]; }
    __syncthreads();
  }
  if (tid == 0) {
    float m = s1[0] / (BB * NN);
    float var = s2[0] / (BB * NN) - m * m;
    smv = m; srv = rsqrtf(var + 1e-5f);
  }
  __syncthreads();
  float m = smv, r = srv;
  for (int i = tid; i < BB * NN; i += 256) {
    int b = i >> 11, n = i & (NN - 1);
    float v = (z[((size_t)b * O + o) * NN + n] - m) * r;
    out[(size_t)b * outBS + (c0 + o) * NN + n] = v >= 0.f ? v : 0.2f * v;
  }
}

// ---------------------------------------------------------------- BN+LReLU into h[:,0:O,:], copy xin into h[:,O:2O,:]
__global__ __launch_bounds__(256) void bn_copy_kernel(const float* __restrict__ z, int O,
                                                      const float* __restrict__ xin, int xbs,
                                                      float* __restrict__ out) {
  int o = blockIdx.x;  // 0..2O-1
  int tid = threadIdx.x;
  int outBS = 2 * O * NN;
  if (o >= O) {
    int c = o - O;
    for (int i = tid; i < BB * NN; i += 256) {
      int b = i >> 11, n = i & (NN - 1);
      out[(size_t)b * outBS + o * NN + n] = xin[(size_t)b * xbs + c * NN + n];
    }
    return;
  }
  __shared__ float s1[256], s2[256];
  __shared__ float smv, srv;
  float a1 = 0.f, a2 = 0.f;
  for (int i = tid; i < BB * NN; i += 256) {
    int b = i >> 11, n = i & (NN - 1);
    float v = z[((size_t)b * O + o) * NN + n];
    a1 += v; a2 += v * v;
  }
  s1[tid] = a1; s2[tid] = a2;
  __syncthreads();
  for (int st = 128; st > 0; st >>= 1) {
    if (tid < st) { s1[tid] += s1[tid + st]; s2[tid] += s2[tid + st]; }
    __syncthreads();
  }
  if (tid == 0) {
    float m = s1[0] / (BB * NN);
    float var = s2[0] / (BB * NN) - m * m;
    smv = m; srv = rsqrtf(var + 1e-5f);
  }
  __syncthreads();
  float m = smv, r = srv;
  for (int i = tid; i < BB * NN; i += 256) {
    int b = i >> 11, n = i & (NN - 1);
    float v = (z[((size_t)b * O + o) * NN + n] - m) * r;
    out[(size_t)b * outBS + o * NN + n] = v >= 0.f ? v : 0.2f * v;
  }
}

// ---------------------------------------------------------------- fused BN+LReLU+max/mean pool (conv5)
__global__ __launch_bounds__(256) void bn_pool_kernel(const float* __restrict__ z,
                                                      float* __restrict__ p) {
  int o = blockIdx.x;
  int tid = threadIdx.x;
  __shared__ float s1[256], s2[256];
  __shared__ float smv, srv;
  float a1 = 0.f, a2 = 0.f;
  for (int i = tid; i < BB * NN; i += 256) {
    int b = i >> 11, n = i & (NN - 1);
    float v = z[((size_t)b * 1024 + o) * NN + n];
    a1 += v; a2 += v * v;
  }
  s1[tid] = a1; s2[tid] = a2;
  __syncthreads();
  for (int st = 128; st > 0; st >>= 1) {
    if (tid < st) { s1[tid] += s1[tid + st]; s2[tid] += s2[tid + st]; }
    __syncthreads();
  }
  if (tid == 0) {
    float m = s1[0] / (BB * NN);
    float var = s2[0] / (BB * NN) - m * m;
    smv = m; srv = rsqrtf(var + 1e-5f);
  }
  __syncthreads();
  float m = smv, r = srv;
  int b = tid >> 5, l = tid & 31;
  const float* zp = z + ((size_t)b * 1024 + o) * NN;
  float mx = -INFINITY, sm = 0.f;
  for (int n = l; n < NN; n += 32) {
    float v = (zp[n] - m) * r;
    v = v >= 0.f ? v : 0.2f * v;
    mx = fmaxf(mx, v); sm += v;
  }
#pragma unroll
  for (int s = 16; s > 0; s >>= 1) {
    mx = fmaxf(mx, __shfl_xor(mx, s));
    sm += __shfl_xor(sm, s);
  }
  if (l == 0) {
    p[b * 2048 + o] = mx;
    p[b * 2048 + 1024 + o] = sm * (1.f / NN);
  }
}

__global__ __launch_bounds__(64) void linear_kernel(const float* __restrict__ in, int IN, int OUT,
                                                    const float* __restrict__ w,
                                                    const float* __restrict__ bias,
                                                    float* __restrict__ out) {
  int o = blockIdx.x;
  int b = o / OUT, f = o % OUT;
  const float* ip = in + (size_t)b * IN;
  const float* wp = w + (size_t)f * IN;
  float a = 0.f;
  for (int i = threadIdx.x; i < IN; i += 64) a += ip[i] * wp[i];
#pragma unroll
  for (int s = 32; s > 0; s >>= 1) a += __shfl_down(a, s);
  if (threadIdx.x == 0) out[o] = a + bias[f];
}

__global__ __launch_bounds__(256) void bnf_kernel(float* __restrict__ t, int F) {
  int f = blockIdx.x * blockDim.x + threadIdx.x;
  if (f >= F) return;
  float s = 0.f, s2 = 0.f;
  for (int b = 0; b < BB; ++b) { float v = t[b * F + f]; s += v; s2 += v * v; }
  float m = s * (1.f / BB);
  float var = s2 * (1.f / BB) - m * m;
  float r = rsqrtf(var + 1e-5f);
  for (int b = 0; b < BB; ++b) {
    float v = (t[b * F + f] - m) * r;
    t[b * F + f] = v >= 0.f ? v : 0.2f * v;
  }
}

// ---------------------------------------------------------------- host side

struct SAW { const float *wq, *wk, *wv, *wc; };

static inline void run_conv(const float* in, int inBS, int C, int O, const float* w,
                            float* z, hipStream_t st) {
  if (O % 128 == 0)
    conv_gemm128_db_kernel<<<dim3(NN / 128, O / 128, BB), 256, 0, st>>>(in, inBS, C, O, w, z);
  else
    conv_gemm_kernel<<<dim3(NN / 64, (O + 63) / 64, BB), 256, 0, st>>>(in, inBS, C, O, w, z);
}

// MFMA==true only valid for C multiple of 128.
template <int C, bool MFMA>
static inline void run_sa(const float* xin, int xbs, SAW w,
                          float* xT, float* U, float* UT, float* AGGt,
                          float* AGG, float* z, float* h, float* sq, int* idx,
                          float* M, float* WCV, unsigned short* Mb, unsigned short* wcvb,
                          unsigned short* xTb, unsigned short* AGGtb,
                          float* D, int nbatch, hipStream_t st) {
  sq_kernel<<<BB * NN / 256, 256, 0, st>>>(xin, xbs, C, sq);
  transpose_kernel<<<dim3(NN / 32, (C + 31) / 32, BB), 256, 0, st>>>(xin, xbs, C, NN, xT);
  mprep_kernel<<<(C * C + 255) / 256, 256, 0, st>>>(w.wq, w.wk, C, M);
  wcv_kernel<<<(C * C + 255) / 256, 256, 0, st>>>(w.wc, w.wv, C, WCV);
  if (MFMA) {
    convert_bf16_kernel<<<(C * C + 255) / 256, 256, 0, st>>>(M, Mb, C * C);
    convert_bf16_kernel<<<(C * C + 255) / 256, 256, 0, st>>>(WCV, wcvb, C * C);
    transpose_bf16_kernel<<<dim3(NN / 32, (C + 31) / 32, BB), 256, 0, st>>>(xin, xbs, C, NN, xTb);
  }
  for (int bb = 0; bb < BB; bb += nbatch) {
    int nbc = (BB - bb) < nbatch ? (BB - bb) : nbatch;
    pd_gemm128_db_kernel<<<dim3(NN / 128, NN / 128, nbc), 256, 0, st>>>(xin, xbs, C, sq, D, bb);
    topk_kernel<<<dim3(NN, nbc), 64, 0, st>>>(D, idx, bb);
  }
  if (MFMA)
    mfma_gemm_lds_kernel<<<dim3(NN / 128, C / 128, BB), 256, 0, st>>>(Mb, xTb, U, C, C);
  else
    run_conv(xin, xbs, C, C, M, U, st);                            // U = M . x  [C][N]
  transpose_kernel<<<dim3(NN / 32, (C + 31) / 32, BB), 256, 0, st>>>(U, C * NN, C, NN, UT);
  att_wave_kernel<C><<<BB * NN, 64, 0, st>>>(xT, UT, idx, AGGt);   // AGGt [N][C]
  if (MFMA) {
    convert_bf16_kernel<<<(BB * NN * C + 255) / 256, 256, 0, st>>>(AGGt, AGGtb, BB * NN * C);
    mfma_gemm_lds_kernel<<<dim3(NN / 128, C / 128, BB), 256, 0, st>>>(wcvb, AGGtb, z, C, C);
  } else {
    transpose_kernel<<<dim3((C + 31) / 32, NN / 32, BB), 256, 0, st>>>(AGGt, NN * C, NN, C, AGG);
    run_conv(AGG, C * NN, C, C, WCV, z, st);                       // Z = (wc.wv) . AGG
  }
  bn_copy_kernel<<<2 * C, 256, 0, st>>>(z, C, xin, xbs, h);
}

static inline void run_conv_bn(const float* in, int inBS, int Cin, int O, const float* w,
                               float* z, float* out, int outBS, int c0, hipStream_t st) {
  run_conv(in, inBS, Cin, O, w, z, st);
  bn_fused_kernel<<<O, 256, 0, st>>>(z, O, out, outBS, c0);
}

extern "C" void kernel_launch(void* const* d_in, const int* in_sizes, int n_in,
                              void* d_out, int out_size, void* d_ws, size_t ws_size,
                              hipStream_t stream) {
  const float* x = (const float*)d_in[0];
  SAW sa1{(const float*)d_in[1], (const float*)d_in[2], (const float*)d_in[3], (const float*)d_in[4]};
  SAW sa2{(const float*)d_in[5], (const float*)d_in[6], (const float*)d_in[7], (const float*)d_in[8]};
  SAW sa3{(const float*)d_in[9], (const float*)d_in[10], (const float*)d_in[11], (const float*)d_in[12]};
  SAW sa4{(const float*)d_in[13], (const float*)d_in[14], (const float*)d_in[15], (const float*)d_in[16]};
  const float* conv1_w = (const float*)d_in[17];
  const float* conv2_w = (const float*)d_in[18];
  const float* conv3_w = (const float*)d_in[19];
  const float* conv4_w = (const float*)d_in[20];
  const float* conv5_w = (const float*)d_in[21];
  const float* lin1_w = (const float*)d_in[22];
  const float* lin1_b = (const float*)d_in[23];
  const float* lin2_w = (const float*)d_in[24];
  const float* lin2_b = (const float*)d_in[25];
  const float* lin3_w = (const float*)d_in[26];
  const float* lin3_b = (const float*)d_in[27];

  char* ws = (char*)d_ws;
  size_t off = 0;
  auto take = [&](size_t bytes) -> void* {
    void* p = ws + off;
    off += (bytes + 255) & ~(size_t)255;
    return p;
  };
  float* sq   = (float*)take((size_t)BB * NN * 4);
  int*   idx  = (int*)take((size_t)BB * NN * KNB * 4);
  float* M    = (float*)take((size_t)128 * 128 * 4);
  float* WCV  = (float*)take((size_t)128 * 128 * 4);
  unsigned short* Mb   = (unsigned short*)take((size_t)128 * 128 * 2);
  unsigned short* wcvb = (unsigned short*)take((size_t)128 * 128 * 2);
  unsigned short* w4b  = (unsigned short*)take((size_t)256 * 256 * 2);
  unsigned short* w5b  = (unsigned short*)take((size_t)1024 * 512 * 2);
  float* U    = (float*)take((size_t)BB * 128 * NN * 4);  // contiguous with AGG
  float* AGG  = (float*)take((size_t)BB * 128 * NN * 4);  // also hosts xT
  float* h    = (float*)take((size_t)BB * 256 * NN * 4);  // first half hosts UT
  float* z    = (float*)take((size_t)BB * 1024 * NN * 4); // hosts AGGt, AGGtb(+16MB), D-chunks
  float* xc   = (float*)take((size_t)BB * 512 * NN * 4);
  float* p    = (float*)take((size_t)BB * 2048 * 4);
  float* t1   = (float*)take((size_t)BB * 512 * 4);
  float* t2   = (float*)take((size_t)BB * 256 * 4);
  (void)n_in; (void)in_sizes; (void)out_size;

  // Overlays (phase-ordered lifetimes):
  float* xT = AGG;                                          // dead before AGG written
  float* UT = h;                                            // consumed before h written
  float* AGGt = z;                                          // first 8.4 MB of z
  unsigned short* xTb   = (unsigned short*)((char*)h + (size_t)BB * 128 * NN * 4);  // h 2nd half
  unsigned short* AGGtb = (unsigned short*)((char*)z + (size_t)16 * 1024 * 1024);   // z + 16 MB
  unsigned short* hTb   = (unsigned short*)U;               // conv4 phase (U dead)
  unsigned short* xcTb  = (unsigned short*)U;               // conv5 phase (U+AGG dead, 16.8 MB)

  size_t dfull = (size_t)BB * NN * NN * 4;
  bool fullD = (ws_size > off + dfull + 4096);
  float* D = fullD ? (float*)take(dfull) : z;               // !fullD: 3-batch chunks in z
  int nbatch = fullD ? BB : 3;

  // SA1 (C=3) -> h [B,6,N]
  run_sa<3, false>(x, 3 * NN, sa1, xT, U, UT, AGGt, AGG, z, h, sq, idx,
                   M, WCV, Mb, wcvb, xTb, AGGtb, D, nbatch, stream);
  run_conv_bn(h, 6 * NN, 6, 64, conv1_w, z, xc, 512 * NN, 0, stream);
  // SA2 (C=64) on x1
  run_sa<64, false>(xc + 0 * NN, 512 * NN, sa2, xT, U, UT, AGGt, AGG, z, h, sq, idx,
                    M, WCV, Mb, wcvb, xTb, AGGtb, D, nbatch, stream);
  run_conv_bn(h, 128 * NN, 128, 64, conv2_w, z, xc, 512 * NN, 64, stream);
  // SA3 (C=64) on x2
  run_sa<64, false>(xc + 64 * NN, 512 * NN, sa3, xT, U, UT, AGGt, AGG, z, h, sq, idx,
                    M, WCV, Mb, wcvb, xTb, AGGtb, D, nbatch, stream);
  run_conv_bn(h, 128 * NN, 128, 128, conv3_w, z, xc, 512 * NN, 128, stream);
  // SA4 (C=128) on x3 — bf16 MFMA for U and Z convs (no kNN downstream)
  run_sa<128, true>(xc + 128 * NN, 512 * NN, sa4, xT, U, UT, AGGt, AGG, z, h, sq, idx,
                    M, WCV, Mb, wcvb, xTb, AGGtb, D, nbatch, stream);
  // conv4 (bf16 MFMA): h [B,256,N] -> z [B,256,N]
  transpose_bf16_kernel<<<dim3(NN / 32, 8, BB), 256, 0, stream>>>(h, 256 * NN, 256, NN, hTb);
  convert_bf16_kernel<<<(256 * 256 + 255) / 256, 256, 0, stream>>>(conv4_w, w4b, 256 * 256);
  mfma_gemm_lds_kernel<<<dim3(NN / 128, 2, BB), 256, 0, stream>>>(w4b, hTb, z, 256, 256);
  bn_fused_kernel<<<256, 256, 0, stream>>>(z, 256, xc, 512 * NN, 256);
  // conv5 (bf16 MFMA): xc [B,512,N] -> z [B,1024,N]; BN+LReLU+pool -> p
  transpose_bf16_kernel<<<dim3(NN / 32, 16, BB), 256, 0, stream>>>(xc, 512 * NN, 512, NN, xcTb);
  convert_bf16_kernel<<<(1024 * 512 + 255) / 256, 256, 0, stream>>>(conv5_w, w5b, 1024 * 512);
  mfma_gemm_lds_kernel<<<dim3(NN / 128, 8, BB), 256, 0, stream>>>(w5b, xcTb, z, 1024, 512);
  bn_pool_kernel<<<1024, 256, 0, stream>>>(z, p);
  // FC head
  linear_kernel<<<BB * 512, 64, 0, stream>>>(p, 2048, 512, lin1_w, lin1_b, t1);
  bnf_kernel<<<2, 256, 0, stream>>>(t1, 512);
  linear_kernel<<<BB * 256, 64, 0, stream>>>(t1, 512, 256, lin2_w, lin2_b, t2);
  bnf_kernel<<<1, 256, 0, stream>>>(t2, 256);
  linear_kernel<<<BB * 40, 64, 0, stream>>>(t2, 256, 40, lin3_w, lin3_b, (float*)d_out);
}